// Round 11
// baseline (732.101 us; speedup 1.0000x reference)
//
#include <hip/hip_runtime.h>
#include <stdint.h>

#define N_NODES 4096
#define NGRAPH 8
#define NPTS 512
#define KNN 64
#define EPSN 1e-5f

typedef _Float16 f16x8 __attribute__((ext_vector_type(8)));
typedef float f32x4 __attribute__((ext_vector_type(4)));
typedef unsigned long long u64;

__device__ __forceinline__ unsigned short f2h(float f) {
    _Float16 h = (_Float16)f;   // RNE, v_cvt_f16_f32
    union { _Float16 h; unsigned short u; } cv; cv.h = h;
    return cv.u;
}

// 16-col blocked layout (for 16x16x32 MFMA)
__device__ __forceinline__ void w2cv(const float* __restrict__ src, unsigned short* __restrict__ dst,
                                     int off, int lg2c) {
    int C = 1 << lg2c;
    int k = off >> lg2c, n = off & (C - 1);
    int d = ((n >> 4) * (C / 32) + (k >> 5)) * 512 + ((k >> 3) & 3) * 128 + (n & 15) * 8 + (k & 7);
    dst[d] = f2h(src[off]);
}

// ---------------- setup: w2 conversions + stat-zero + gn1 stats + kNN, one dispatch ----------------
__global__ __launch_bounds__(64) void setup_kernel(const float* __restrict__ pos, int* __restrict__ knn_out,
                                                   const float* __restrict__ wa, const float* __restrict__ wb,
                                                   const float* __restrict__ wc, const float* __restrict__ wd,
                                                   const float* __restrict__ we,
                                                   unsigned short* __restrict__ oa, unsigned short* __restrict__ ob,
                                                   unsigned short* __restrict__ oc, unsigned short* __restrict__ od,
                                                   unsigned short* __restrict__ oe,
                                                   float* __restrict__ statz,
                                                   const float* __restrict__ ms1, const float* __restrict__ gw1,
                                                   float* __restrict__ Aa, float* __restrict__ Sa) {
#pragma clang fp contract(off)
    __shared__ float px[NPTS], py[NPTS], pz[NPTS];
    __shared__ u64 keys[NPTS];
    int bid = blockIdx.x;
    int tid = threadIdx.x;   // 0..63
    int gidx = bid * 64 + tid;           // 0..262143
    for (int idx = gidx; idx < 40960; idx += 262144) statz[idx] = 0.f;
    for (int idx = gidx; idx < 610304; idx += 262144) {
        if (idx < 4096)        w2cv(wa, oa, idx, 6);
        else if (idx < 20480)  w2cv(wb, ob, idx - 4096, 7);
        else if (idx < 86016)  w2cv(wc, oc, idx - 20480, 8);
        else if (idx < 348160) w2cv(wd, od, idx - 86016, 9);
        else                   w2cv(we, oe, idx - 348160, 9);
    }
    if (bid < 24) {   // gn1 stats: 24 (graph,channel) wave-jobs
        int g = bid / 3, ch = bid - g * 3;
        float s1 = 0.f, s2 = 0.f;
        for (int n = tid; n < NPTS; n += 64) {
            float v = pos[(g * NPTS + n) * 3 + ch];
            s1 += v; s2 += v * v;
        }
        #pragma unroll
        for (int off = 32; off; off >>= 1) { s1 += __shfl_xor(s1, off); s2 += __shfl_xor(s2, off); }
        if (tid == 0) {
            float mean = s1 * (1.f / NPTS);
            float av = mean * ms1[ch];
            float var = s2 * (1.f / NPTS) - 2.f * av * mean + av * av;
            Aa[g * 3 + ch] = av;
            Sa[g * 3 + ch] = gw1[ch] / sqrtf(var + EPSN);
        }
    }
    // ---- kNN: 1-wave bitonic sort of this dst point's 512 keys ----
    int b = bid >> 9;
    int il = bid & (NPTS - 1);
    for (int n = tid; n < NPTS; n += 64) {
        int base = (b * NPTS + n) * 3;
        px[n] = pos[base]; py[n] = pos[base + 1]; pz[n] = pos[base + 2];
    }
    __syncthreads();
    float xi = px[il], yi = py[il], zi = pz[il];
    for (int n = tid; n < NPTS; n += 64) {
        float dx = px[n] - xi, dy = py[n] - yi, dz = pz[n] - zi;
        float d2 = dx * dx;
        d2 = d2 + dy * dy;
        d2 = d2 + dz * dz;
        keys[n] = (((u64)__float_as_uint(d2)) << 32) | (unsigned)n;
    }
    __syncthreads();
    for (int k2 = 2; k2 <= NPTS; k2 <<= 1) {
        for (int j = k2 >> 1; j > 0; j >>= 1) {
            #pragma unroll 4
            for (int p = 0; p < 4; ++p) {
                int pid = tid + p * 64;
                int t = ((pid & ~(j - 1)) << 1) | (pid & (j - 1));
                int ixj = t | j;
                u64 a = keys[t], c = keys[ixj];
                bool up = ((t & k2) == 0);
                if ((a > c) == up) { keys[t] = c; keys[ixj] = a; }
            }
            __syncthreads();
        }
    }
    int j0 = (int)(keys[tid] & 0xffffffffu);
    knn_out[(size_t)(b * NPTS + il) * KNN + tid] = b * NPTS + j0;
}

// ---------------- Per-node MLP1 with fused GraphNorm apply on input ----------------
template<int CIN, int C, int RELU, int RAW>
__global__ __launch_bounds__(C) void node_kernel(const float* __restrict__ y, const float* __restrict__ pos,
                                                 const float* __restrict__ p1, const float* __restrict__ p2,
                                                 const float* __restrict__ ms, const float* __restrict__ gw,
                                                 const float* __restrict__ bnp,
                                                 const float* __restrict__ w1, const float* __restrict__ b1,
                                                 float* __restrict__ U, float* __restrict__ P) {
    constexpr int ROWS = 16;
    constexpr int KC = 64;
    constexpr int LDH = KC + 4;
    __shared__ float hs[ROWS][LDH];   // 4352 B
    __shared__ float As_[CIN > 0 ? CIN : 1], Ss_[CIN > 0 ? CIN : 1];
    const int c = threadIdx.x;
    const int n0 = blockIdx.x * ROWS;
    const int b = n0 >> 9;            // all 16 rows in one graph
    if (RAW) {
        for (int ch = c; ch < CIN; ch += C) {
            float s1 = p1[b * CIN + ch], s2 = p2[b * CIN + ch];
            float mean = s1 * (1.f / NPTS);
            float a = mean * ms[ch];
            float var = s2 * (1.f / NPTS) - 2.f * a * mean + a * a;
            As_[ch] = a;
            Ss_[ch] = gw[ch] / sqrtf(var + EPSN);
        }
    }
    float acc[ROWS];
    #pragma unroll
    for (int r = 0; r < ROWS; ++r) acc[r] = 0.f;
    constexpr int NCHUNK = (CIN + KC - 1) / KC;
    #pragma unroll 1
    for (int s = 0; s < NCHUNK; ++s) {
        const int k0 = s * KC;
        const int kc = (CIN - k0 < KC) ? (CIN - k0) : KC;
        __syncthreads();
        for (int idx = c; idx < ROWS * kc; idx += C) {
            int r = idx / kc, k = idx - r * kc;
            int ch = k0 + k;
            float a = RAW ? As_[ch] : p1[b * CIN + ch];
            float sf = RAW ? Ss_[ch] : p2[b * CIN + ch];
            float v = (y[(size_t)(n0 + r) * CIN + ch] - a) * sf + bnp[ch];
            if (RELU) v = fmaxf(v, 0.f);
            hs[r][k] = v;
        }
        __syncthreads();
        int k = 0;
        for (; k + 4 <= kc; k += 4) {
            float w0 = w1[(size_t)(k0 + k) * C + c];
            float w1v = w1[(size_t)(k0 + k + 1) * C + c];
            float w2v = w1[(size_t)(k0 + k + 2) * C + c];
            float w3v = w1[(size_t)(k0 + k + 3) * C + c];
            #pragma unroll
            for (int r = 0; r < ROWS; ++r) {
                f32x4 hv = *(const f32x4*)&hs[r][k];
                acc[r] = fmaf(hv[0], w0, acc[r]);
                acc[r] = fmaf(hv[1], w1v, acc[r]);
                acc[r] = fmaf(hv[2], w2v, acc[r]);
                acc[r] = fmaf(hv[3], w3v, acc[r]);
            }
        }
        for (; k < kc; ++k) {
            float wv = w1[(size_t)(k0 + k) * C + c];
            #pragma unroll
            for (int r = 0; r < ROWS; ++r)
                acc[r] = fmaf(hs[r][k], wv, acc[r]);
        }
    }
    float pacc[ROWS];
    #pragma unroll
    for (int r = 0; r < ROWS; ++r) pacc[r] = 0.f;
    #pragma unroll
    for (int e = 0; e < 3; ++e) {
        float wv = w1[(size_t)(CIN + e) * C + c];
        #pragma unroll
        for (int r = 0; r < ROWS; ++r)
            pacc[r] = fmaf(pos[(n0 + r) * 3 + e], wv, pacc[r]);
    }
    float bv = b1[c];
    #pragma unroll
    for (int r = 0; r < ROWS; ++r) {
        U[(size_t)(n0 + r) * C + c] = acc[r] + pacc[r] + bv;
        P[(size_t)(n0 + r) * C + c] = pacc[r];
    }
}

// ---------------- Edge MLP2 (small C): round-2 proven monolithic-stage kernel ----------------
template<int C, int W>
__global__ __launch_bounds__(W * 64, 4) void edge_kernel(const float* __restrict__ U, const float* __restrict__ P,
                                                         const int* __restrict__ knn, const unsigned short* __restrict__ w2t,
                                                         const float* __restrict__ b2, float* __restrict__ Y,
                                                         float* __restrict__ sum1, float* __restrict__ sum2) {
    constexpr int NCT = C / (W * 16);    // col tiles per wave
    constexpr int S32 = C / 32;          // k32 tiles
    constexpr int NCHUNK = C / 8;        // 16B chunks per row
    __shared__ unsigned short Th[64 * C];   // full message tile, swizzled
    __shared__ int jn[64];
    __shared__ float Pr[C];              // block-uniform dst-row of P
    const int bid = blockIdx.x;
    const int i = ((bid & 7) << 9) | (bid >> 3);   // XCD = bid%8 = graph(i): gather stays in one L2
    const int tid = threadIdx.x;
    const int wave = tid >> 6, lane = tid & 63, m = lane & 15, quad = lane >> 4;
    const int cw = wave * (NCT * 16);
    if (tid < 64) jn[tid] = knn[(size_t)i * KNN + tid];
    for (int idx = tid; idx < C; idx += W * 64) Pr[idx] = P[(size_t)i * C + idx];
    __syncthreads();                     // jn + Pr visible
    #pragma unroll 2
    for (int idx = tid; idx < 64 * NCHUNK; idx += W * 64) {
        int row = idx / NCHUNK, ch = idx - row * NCHUNK;
        const float* up = U + (size_t)jn[row] * C + ch * 8;
        f32x4 va = *(const f32x4*)up;
        f32x4 vb = *(const f32x4*)(up + 4);
        f32x4 pa = *(const f32x4*)&Pr[ch * 8];
        f32x4 pb = *(const f32x4*)&Pr[ch * 8 + 4];
        uint4 pk;
        pk.x = (unsigned)f2h(fmaxf(va[0] - pa[0], 0.f)) | ((unsigned)f2h(fmaxf(va[1] - pa[1], 0.f)) << 16);
        pk.y = (unsigned)f2h(fmaxf(va[2] - pa[2], 0.f)) | ((unsigned)f2h(fmaxf(va[3] - pa[3], 0.f)) << 16);
        pk.z = (unsigned)f2h(fmaxf(vb[0] - pb[0], 0.f)) | ((unsigned)f2h(fmaxf(vb[1] - pb[1], 0.f)) << 16);
        pk.w = (unsigned)f2h(fmaxf(vb[2] - pb[2], 0.f)) | ((unsigned)f2h(fmaxf(vb[3] - pb[3], 0.f)) << 16);
        int sc = (ch & ~7) | ((ch ^ row) & 7);
        *(uint4*)&Th[row * C + sc * 8] = pk;
    }
    __syncthreads();
    f32x4 acc[4][NCT];
    f32x4 zero = {0.f, 0.f, 0.f, 0.f};
    #pragma unroll
    for (int rt = 0; rt < 4; ++rt)
        #pragma unroll
        for (int ct = 0; ct < NCT; ++ct)
            acc[rt][ct] = zero;
    #pragma unroll 2
    for (int s = 0; s < S32; ++s) {
        f16x8 a[4];
        #pragma unroll
        for (int rt = 0; rt < 4; ++rt) {
            int row = rt * 16 + m;
            int chunk = s * 4 + quad;
            int sc = (chunk & ~7) | ((chunk ^ row) & 7);
            a[rt] = *(const f16x8*)&Th[row * C + sc * 8];
        }
        #pragma unroll
        for (int ct = 0; ct < NCT; ++ct) {
            const f16x8 bb = *(const f16x8*)(w2t +
                (size_t)(((cw >> 4) + ct) * S32 + s) * 512 + quad * 128 + m * 8);
            #pragma unroll
            for (int rt = 0; rt < 4; ++rt)
                acc[rt][ct] = __builtin_amdgcn_mfma_f32_16x16x32_f16(a[rt], bb, acc[rt][ct], 0, 0, 0);
        }
    }
    const int gb = i >> 9;
    #pragma unroll
    for (int ct = 0; ct < NCT; ++ct) {
        float vmax = -3.4e38f;
        #pragma unroll
        for (int rt = 0; rt < 4; ++rt) {
            vmax = fmaxf(vmax, acc[rt][ct][0]);
            vmax = fmaxf(vmax, acc[rt][ct][1]);
            vmax = fmaxf(vmax, acc[rt][ct][2]);
            vmax = fmaxf(vmax, acc[rt][ct][3]);
        }
        vmax = fmaxf(vmax, __shfl_xor(vmax, 16));
        vmax = fmaxf(vmax, __shfl_xor(vmax, 32));
        if (quad == 0) {
            int col = cw + ct * 16 + m;
            float val = vmax + b2[col];
            Y[(size_t)i * C + col] = val;
            atomicAdd(&sum1[gb * C + col], val);
            atomicAdd(&sum2[gb * C + col], val * val);
        }
    }
}

__device__ __forceinline__ uint4 pack8(f32x4 va, f32x4 vb, f32x4 pa, f32x4 pb) {
    uint4 pk;
    pk.x = (unsigned)f2h(fmaxf(va[0] - pa[0], 0.f)) | ((unsigned)f2h(fmaxf(va[1] - pa[1], 0.f)) << 16);
    pk.y = (unsigned)f2h(fmaxf(va[2] - pa[2], 0.f)) | ((unsigned)f2h(fmaxf(va[3] - pa[3], 0.f)) << 16);
    pk.z = (unsigned)f2h(fmaxf(vb[0] - pb[0], 0.f)) | ((unsigned)f2h(fmaxf(vb[1] - pb[1], 0.f)) << 16);
    pk.w = (unsigned)f2h(fmaxf(vb[2] - pb[2], 0.f)) | ((unsigned)f2h(fmaxf(vb[3] - pb[3], 0.f)) << 16);
    return pk;
}

// ---------------- Edge MLP2 (large C): 16 waves (1024 threads) share one A-tile -> 4 waves/SIMD.
// Round 9 ran 2 waves/SIMD (252 regs/wave incl. AGPR) and plateaued at 41% MfmaUtil with all
// operand streams pipelined -> lockstep-wave starvation, not prefetch depth. Now: 2M x 8N wave
// grid, per wave 64 rows x C/8 cols -> acc 4xNCTx4 = 64 AGPR; B 1-deep prefetch (cover = one
// full step period >> L2 latency); idx parity via idx^32 (algebra: (4^quad)^(row&7) = 4^(quad^
// (row&7))). Target <=128 regs/wave -> 16 waves/CU. Same proven swizzle (0 conflicts measured).
template<int C>
__global__ __launch_bounds__(1024, 4) void edgeb_kernel(const float* __restrict__ U, const float* __restrict__ P,
                                                        const int* __restrict__ knn, const unsigned short* __restrict__ w2t,
                                                        const float* __restrict__ b2, float* __restrict__ Y,
                                                        float* __restrict__ sum1, float* __restrict__ sum2) {
    constexpr int NCT = C / 128;         // col tiles per wave (8 col-groups of C/8)
    constexpr int S32 = C / 32;          // k32 tiles total
    constexpr int NCHK = C / 8;          // 16B chunks per row
    constexpr int RSTEP = 1024 / NCHK;   // staging rows per iteration
    __shared__ unsigned short Th[(C / 64) * 128 * 64];   // chunk-major swizzled A-tile
    __shared__ int jn[128];
    const int bid = blockIdx.x;
    const int g = bid & 7;               // XCD = graph: U/P/w2t stay in one L2
    const int n0 = (g << 9) | ((bid >> 3) << 1);   // first of 2 dst nodes
    const int tid = threadIdx.x;
    const int lane = tid & 63, wave = tid >> 6, m = lane & 15, quad = lane >> 4;
    const int wrow = wave >> 3;          // M-group: rows [wrow*64, wrow*64+64) = node n0+wrow
    const int wcol = wave & 7;           // N-group: cols [wcol*(C/8), ...)
    const int cw = wcol * (NCT * 16);
    if (tid < 128) jn[tid] = knn[(size_t)(n0 + (tid >> 6)) * KNN + (tid & 63)];
    // per-thread fixed staging columns -> P values in registers (loaded once, pre-barrier)
    const int ch = tid & (NCHK - 1);     // chunk 0..NCHK-1
    const int rb = tid / NCHK;           // staging row base
    const int cblk = ch >> 3, cw8 = ch & 7;
    const float* pp = P + (size_t)n0 * C + ch * 8;
    f32x4 pa0 = *(const f32x4*)pp;
    f32x4 pb0 = *(const f32x4*)(pp + 4);
    f32x4 pa1 = *(const f32x4*)(pp + C);
    f32x4 pb1 = *(const f32x4*)(pp + C + 4);
    __syncthreads();                     // jn visible
    // ---- stage all 128 rows x C cols as f16 messages (measured: 0 bank conflicts) ----
    #pragma unroll 4
    for (int t = 0; t < 128 / RSTEP; ++t) {
        int row = rb + t * RSTEP;
        const float* up = U + (size_t)jn[row] * C + ch * 8;
        f32x4 va = *(const f32x4*)up;
        f32x4 vb = *(const f32x4*)(up + 4);
        f32x4 pa = (row & 64) ? pa1 : pa0;
        f32x4 pb = (row & 64) ? pb1 : pb0;
        *(uint4*)&Th[cblk * 8192 + row * 64 + ((cw8 ^ (row & 7)) << 3)] = pack8(va, vb, pa, pb);
    }
    __syncthreads();
    // ---- barrier-free MFMA sweep: per wave 4 row-tiles x NCT col-tiles, 1-deep B prefetch ----
    f32x4 acc[4][NCT];
    f32x4 zero = {0.f, 0.f, 0.f, 0.f};
    #pragma unroll
    for (int rt = 0; rt < 4; ++rt)
        #pragma unroll
        for (int ct = 0; ct < NCT; ++ct)
            acc[rt][ct] = zero;
    const unsigned short* wt = w2t + (size_t)(cw >> 4) * S32 * 512 + quad * 128 + m * 8;
    int idx0[4];                         // A-tile element indices (even step parity; odd = ^32)
    #pragma unroll
    for (int rt = 0; rt < 4; ++rt) {
        int row = wrow * 64 + rt * 16 + m;
        idx0[rt] = row * 64 + ((quad ^ (row & 7)) << 3);
    }
    const unsigned short* pB[NCT];       // prefetch pointers (s+1 targets at loop entry)
    #pragma unroll
    for (int ct = 0; ct < NCT; ++ct)
        pB[ct] = wt + ((size_t)ct * S32 + 1) * 512;
    f16x8 bb[NCT];
    #pragma unroll
    for (int ct = 0; ct < NCT; ++ct)
        bb[ct] = *(const f16x8*)(wt + (size_t)ct * S32 * 512);
    const unsigned short* tcur = Th;     // = Th + (s>>1)*8192
    auto stepf = [&](int axor, int poff, bool pre) {
        f16x8 a[4];
        #pragma unroll
        for (int rt = 0; rt < 4; ++rt)
            a[rt] = *(const f16x8*)&tcur[idx0[rt] ^ axor];
        #pragma unroll
        for (int ct = 0; ct < NCT; ++ct) {
            f16x8 bcur = bb[ct];
            if (pre) bb[ct] = *(const f16x8*)(pB[ct] + poff);
            __builtin_amdgcn_s_setprio(1);
            #pragma unroll
            for (int rt = 0; rt < 4; ++rt)
                acc[rt][ct] = __builtin_amdgcn_mfma_f32_16x16x32_f16(a[rt], bcur, acc[rt][ct], 0, 0, 0);
            __builtin_amdgcn_s_setprio(0);
        }
    };
    #pragma unroll 1
    for (int s = 0; s + 2 <= S32; s += 2) {
        stepf(0, 0, true);               // consume s,   prefetch s+1
        stepf(32, 512, s + 2 < S32);     // consume s+1, prefetch s+2 (guarded at tail)
        tcur += 8192;
        #pragma unroll
        for (int ct = 0; ct < NCT; ++ct) pB[ct] += 1024;
    }
    // ---- epilogue: this wave's node is n0+wrow; scatter-max over its 4 row-tiles ----
    #pragma unroll
    for (int ct = 0; ct < NCT; ++ct) {
        float vmax = -3.4e38f;
        #pragma unroll
        for (int rt = 0; rt < 4; ++rt) {
            vmax = fmaxf(vmax, acc[rt][ct][0]);
            vmax = fmaxf(vmax, acc[rt][ct][1]);
            vmax = fmaxf(vmax, acc[rt][ct][2]);
            vmax = fmaxf(vmax, acc[rt][ct][3]);
        }
        vmax = fmaxf(vmax, __shfl_xor(vmax, 16));
        vmax = fmaxf(vmax, __shfl_xor(vmax, 32));
        if (quad == 0) {
            int col = cw + ct * 16 + m;
            float val = vmax + b2[col];
            Y[(size_t)(n0 + wrow) * C + col] = val;
            atomicAdd(&sum1[g * C + col], val);
            atomicAdd(&sum2[g * C + col], val * val);
        }
    }
}

// ---------------- Classifier with fused gn6 (stats from atomic sums) ----------------
__global__ __launch_bounds__(256) void cls_kernel(const float* __restrict__ y, const float* __restrict__ sum1,
                                                  const float* __restrict__ sum2, const float* __restrict__ ms,
                                                  const float* __restrict__ gw, const float* __restrict__ gnb,
                                                  const float* __restrict__ w, const float* __restrict__ bias,
                                                  float* __restrict__ out) {
    __shared__ float wl[512 * 14];      // 28672 B
    __shared__ _Float16 hn[16][520];    // 16640 B (pad 8 -> 2-way LDS aliasing only)
    __shared__ float As[512], Ss[512];  // 4096 B
    int tid = threadIdx.x;
    int n0 = blockIdx.x * 16;
    int b = n0 >> 9;
    for (int ch = tid; ch < 512; ch += 256) {
        float s1 = sum1[b * 512 + ch], s2 = sum2[b * 512 + ch];
        float mean = s1 * (1.f / NPTS);
        float a = mean * ms[ch];
        float var = s2 * (1.f / NPTS) - 2.f * a * mean + a * a;
        As[ch] = a;
        Ss[ch] = gw[ch] / sqrtf(var + EPSN);
    }
    for (int idx = tid; idx < 512 * 14; idx += 256) wl[idx] = w[idx];
    __syncthreads();
    for (int idx = tid; idx < 16 * 512; idx += 256) {
        int r = idx >> 9, k = idx & 511;
        float v = (y[(size_t)(n0 + r) * 512 + k] - As[k]) * Ss[k] + gnb[k];
        hn[r][k] = (_Float16)fmaxf(v, 0.f);
    }
    __syncthreads();
    if (tid < 224) {
        int nl = tid / 14, c = tid - nl * 14;
        float acc = bias[c];
        for (int k = 0; k < 512; ++k)
            acc += (float)hn[nl][k] * wl[k * 14 + c];
        out[(size_t)(n0 + nl) * 14 + c] = acc;
    }
}

extern "C" void kernel_launch(void* const* d_in, const int* in_sizes, int n_in,
                              void* d_out, int out_size, void* d_ws, size_t ws_size,
                              hipStream_t stream) {
    const float* pos = (const float*)d_in[0];
    const float* gnw[6]; const float* gnb[6]; const float* gnms[6];
    for (int i = 0; i < 6; ++i) {
        gnw[i]  = (const float*)d_in[2 + 3 * i];
        gnb[i]  = (const float*)d_in[3 + 3 * i];
        gnms[i] = (const float*)d_in[4 + 3 * i];
    }
    const float* cw1[5]; const float* cb1[5]; const float* cw2[5]; const float* cb2[5];
    for (int i = 0; i < 5; ++i) {
        cw1[i] = (const float*)d_in[20 + 4 * i];
        cb1[i] = (const float*)d_in[21 + 4 * i];
        cw2[i] = (const float*)d_in[22 + 4 * i];
        cb2[i] = (const float*)d_in[23 + 4 * i];
    }
    const float* clsw = (const float*)d_in[40];
    const float* clsb = (const float*)d_in[41];
    float* out = (float*)d_out;

    char* ws = (char*)d_ws;
    int* knn             = (int*)(ws + 0);                 // 1 MB
    float* U             = (float*)(ws + 1048576);         // 8 MB
    float* P             = (float*)(ws + 9437184);         // 8 MB
    float* y             = (float*)(ws + 26214400);        // 8 MB
    float* Aa            = (float*)(ws + 34603008);        // 16 KB
    float* Sa            = (float*)(ws + 34619392);        // 16 KB
    unsigned short* w2t0 = (unsigned short*)(ws + 34635776);  // 8 KB
    unsigned short* w2t1 = (unsigned short*)(ws + 34643968);  // 32 KB
    unsigned short* w2t2 = (unsigned short*)(ws + 34676736);  // 128 KB
    unsigned short* w2t3 = (unsigned short*)(ws + 34807808);  // 512 KB
    unsigned short* w2t4 = (unsigned short*)(ws + 35332096);  // 512 KB
    float* acc           = (float*)(ws + 35856384);           // 160 KB: 5 x (4096+4096) floats
    float* s1l[5]; float* s2l[5];
    for (int l = 0; l < 5; ++l) { s1l[l] = acc + l * 8192; s2l[l] = s1l[l] + 4096; }

    // setup: w2 conversions + stat-zero + gn1 stats + kNN
    setup_kernel<<<N_NODES, 64, 0, stream>>>(pos, knn, cw2[0], cw2[1], cw2[2], cw2[3], cw2[4],
                                             w2t0, w2t1, w2t2, w2t3, w2t4, acc,
                                             gnms[0], gnw[0], Aa, Sa);

    // Layer 1 (gn1 apply fused into node1, no relu)
    node_kernel<3, 64, 0, 0><<<N_NODES / 16, 64, 0, stream>>>(pos, pos, Aa, Sa, gnms[0], gnw[0], gnb[0], cw1[0], cb1[0], U, P);
    edge_kernel<64, 4><<<N_NODES, 256, 0, stream>>>(U, P, knn, w2t0, cb2[0], y, s1l[0], s2l[0]);

    // Layer 2 (stats from L1 edge atomics)
    node_kernel<64, 128, 1, 1><<<N_NODES / 16, 128, 0, stream>>>(y, pos, s1l[0], s2l[0], gnms[1], gnw[1], gnb[1], cw1[1], cb1[1], U, P);
    edge_kernel<128, 8><<<N_NODES, 512, 0, stream>>>(U, P, knn, w2t1, cb2[1], y, s1l[1], s2l[1]);

    // Layer 3
    node_kernel<128, 256, 1, 1><<<N_NODES / 16, 256, 0, stream>>>(y, pos, s1l[1], s2l[1], gnms[2], gnw[2], gnb[2], cw1[2], cb1[2], U, P);
    edgeb_kernel<256><<<N_NODES / 2, 1024, 0, stream>>>(U, P, knn, w2t2, cb2[2], y, s1l[2], s2l[2]);

    // Layer 4
    node_kernel<256, 512, 1, 1><<<N_NODES / 16, 512, 0, stream>>>(y, pos, s1l[2], s2l[2], gnms[3], gnw[3], gnb[3], cw1[3], cb1[3], U, P);
    edgeb_kernel<512><<<N_NODES / 2, 1024, 0, stream>>>(U, P, knn, w2t3, cb2[3], y, s1l[3], s2l[3]);

    // Layer 5
    node_kernel<512, 512, 1, 1><<<N_NODES / 16, 512, 0, stream>>>(y, pos, s1l[3], s2l[3], gnms[4], gnw[4], gnb[4], cw1[4], cb1[4], U, P);
    edgeb_kernel<512><<<N_NODES / 2, 1024, 0, stream>>>(U, P, knn, w2t4, cb2[4], y, s1l[4], s2l[4]);

    // gn6 (stats from L5 edge atomics) fused into classifier
    cls_kernel<<<N_NODES / 16, 256, 0, stream>>>(y, s1l[4], s2l[4], gnms[5], gnw[5], gnb[5], clsw, clsb, out);
}

// Round 12
// 700.637 us; speedup vs baseline: 1.0449x; 1.0449x over previous
//
#include <hip/hip_runtime.h>
#include <stdint.h>

#define N_NODES 4096
#define NGRAPH 8
#define NPTS 512
#define KNN 64
#define EPSN 1e-5f

typedef _Float16 f16x8 __attribute__((ext_vector_type(8)));
typedef float f32x4 __attribute__((ext_vector_type(4)));
typedef unsigned long long u64;

__device__ __forceinline__ unsigned short f2h(float f) {
    _Float16 h = (_Float16)f;   // RNE, v_cvt_f16_f32
    union { _Float16 h; unsigned short u; } cv; cv.h = h;
    return cv.u;
}

// Chunk-major w2 conversion: one thread produces one 16-half chunk of the 16-col blocked
// layout (8 strided coalesced-ish reads -> 1 coalesced 16B write). Replaces the scattered
// 2B-store w2cv (610k isolated stores, no write combining).
// Layout check: d(k,n) = ((n>>4)*(C/32)+(k>>5))*512 + ((k>>3)&3)*128 + (n&15)*8 + (k&7)
//   chunk c = F*64 + q*16 + mm with F=(n>>4)*(C/32)+(k>>5), q=(k>>3)&3, mm=n&15.
__device__ __forceinline__ void w2cv8(const float* __restrict__ src, unsigned short* __restrict__ dst,
                                      int c, int lg2c) {
    int C = 1 << lg2c;
    int mm = c & 15, q = (c >> 4) & 3, F = c >> 6;
    int k5 = F & ((C >> 5) - 1), n4 = F >> (lg2c - 5);
    int n = n4 * 16 + mm, kb = k5 * 32 + q * 8;
    unsigned short h[8];
    #pragma unroll
    for (int t = 0; t < 8; ++t) h[t] = f2h(src[(size_t)(kb + t) * C + n]);
    uint4 pk;
    pk.x = (unsigned)h[0] | ((unsigned)h[1] << 16);
    pk.y = (unsigned)h[2] | ((unsigned)h[3] << 16);
    pk.z = (unsigned)h[4] | ((unsigned)h[5] << 16);
    pk.w = (unsigned)h[6] | ((unsigned)h[7] << 16);
    *(uint4*)&dst[(size_t)c * 8] = pk;
}

// ---------------- setup: w2 conversions + stat-zero + gn1 stats + kNN, one dispatch ----------------
__global__ __launch_bounds__(64) void setup_kernel(const float* __restrict__ pos, int* __restrict__ knn_out,
                                                   const float* __restrict__ wa, const float* __restrict__ wb,
                                                   const float* __restrict__ wc, const float* __restrict__ wd,
                                                   const float* __restrict__ we,
                                                   unsigned short* __restrict__ oa, unsigned short* __restrict__ ob,
                                                   unsigned short* __restrict__ oc, unsigned short* __restrict__ od,
                                                   unsigned short* __restrict__ oe,
                                                   float* __restrict__ statz,
                                                   const float* __restrict__ ms1, const float* __restrict__ gw1,
                                                   float* __restrict__ Aa, float* __restrict__ Sa) {
#pragma clang fp contract(off)
    __shared__ float px[NPTS], py[NPTS], pz[NPTS];
    __shared__ u64 keys[NPTS];
    int bid = blockIdx.x;
    int tid = threadIdx.x;   // 0..63
    int gidx = bid * 64 + tid;           // 0..262143
    for (int idx = gidx; idx < 40960; idx += 262144) statz[idx] = 0.f;
    // w2 conversions: 76288 chunks (all < 262144 -> single pass)
    // chunk starts: wa 0, wb 512, wc 2560, wd 10752, we 43520, end 76288
    if (gidx < 76288) {
        int c = gidx;
        if (c < 512)         w2cv8(wa, oa, c, 6);
        else if (c < 2560)   w2cv8(wb, ob, c - 512, 7);
        else if (c < 10752)  w2cv8(wc, oc, c - 2560, 8);
        else if (c < 43520)  w2cv8(wd, od, c - 10752, 9);
        else                 w2cv8(we, oe, c - 43520, 9);
    }
    if (bid < 24) {   // gn1 stats: 24 (graph,channel) wave-jobs
        int g = bid / 3, ch = bid - g * 3;
        float s1 = 0.f, s2 = 0.f;
        for (int n = tid; n < NPTS; n += 64) {
            float v = pos[(g * NPTS + n) * 3 + ch];
            s1 += v; s2 += v * v;
        }
        #pragma unroll
        for (int off = 32; off; off >>= 1) { s1 += __shfl_xor(s1, off); s2 += __shfl_xor(s2, off); }
        if (tid == 0) {
            float mean = s1 * (1.f / NPTS);
            float av = mean * ms1[ch];
            float var = s2 * (1.f / NPTS) - 2.f * av * mean + av * av;
            Aa[g * 3 + ch] = av;
            Sa[g * 3 + ch] = gw1[ch] / sqrtf(var + EPSN);
        }
    }
    // ---- kNN: 1-wave bitonic sort of this dst point's 512 keys ----
    int b = bid >> 9;
    int il = bid & (NPTS - 1);
    for (int n = tid; n < NPTS; n += 64) {
        int base = (b * NPTS + n) * 3;
        px[n] = pos[base]; py[n] = pos[base + 1]; pz[n] = pos[base + 2];
    }
    __syncthreads();
    float xi = px[il], yi = py[il], zi = pz[il];
    for (int n = tid; n < NPTS; n += 64) {
        float dx = px[n] - xi, dy = py[n] - yi, dz = pz[n] - zi;
        float d2 = dx * dx;
        d2 = d2 + dy * dy;
        d2 = d2 + dz * dz;
        keys[n] = (((u64)__float_as_uint(d2)) << 32) | (unsigned)n;
    }
    __syncthreads();
    for (int k2 = 2; k2 <= NPTS; k2 <<= 1) {
        for (int j = k2 >> 1; j > 0; j >>= 1) {
            #pragma unroll 4
            for (int p = 0; p < 4; ++p) {
                int pid = tid + p * 64;
                int t = ((pid & ~(j - 1)) << 1) | (pid & (j - 1));
                int ixj = t | j;
                u64 a = keys[t], c = keys[ixj];
                bool up = ((t & k2) == 0);
                if ((a > c) == up) { keys[t] = c; keys[ixj] = a; }
            }
            __syncthreads();
        }
    }
    int j0 = (int)(keys[tid] & 0xffffffffu);
    knn_out[(size_t)(b * NPTS + il) * KNN + tid] = b * NPTS + j0;
}

// ---------------- Per-node MLP1 with fused GraphNorm apply on input ----------------
template<int CIN, int C, int RELU, int RAW>
__global__ __launch_bounds__(C) void node_kernel(const float* __restrict__ y, const float* __restrict__ pos,
                                                 const float* __restrict__ p1, const float* __restrict__ p2,
                                                 const float* __restrict__ ms, const float* __restrict__ gw,
                                                 const float* __restrict__ bnp,
                                                 const float* __restrict__ w1, const float* __restrict__ b1,
                                                 float* __restrict__ U, float* __restrict__ P) {
    constexpr int ROWS = 16;
    constexpr int KC = 64;
    constexpr int LDH = KC + 4;
    __shared__ float hs[ROWS][LDH];   // 4352 B
    __shared__ float As_[CIN > 0 ? CIN : 1], Ss_[CIN > 0 ? CIN : 1];
    const int c = threadIdx.x;
    const int n0 = blockIdx.x * ROWS;
    const int b = n0 >> 9;            // all 16 rows in one graph
    if (RAW) {
        for (int ch = c; ch < CIN; ch += C) {
            float s1 = p1[b * CIN + ch], s2 = p2[b * CIN + ch];
            float mean = s1 * (1.f / NPTS);
            float a = mean * ms[ch];
            float var = s2 * (1.f / NPTS) - 2.f * a * mean + a * a;
            As_[ch] = a;
            Ss_[ch] = gw[ch] / sqrtf(var + EPSN);
        }
    }
    float acc[ROWS];
    #pragma unroll
    for (int r = 0; r < ROWS; ++r) acc[r] = 0.f;
    constexpr int NCHUNK = (CIN + KC - 1) / KC;
    #pragma unroll 1
    for (int s = 0; s < NCHUNK; ++s) {
        const int k0 = s * KC;
        const int kc = (CIN - k0 < KC) ? (CIN - k0) : KC;
        __syncthreads();
        for (int idx = c; idx < ROWS * kc; idx += C) {
            int r = idx / kc, k = idx - r * kc;
            int ch = k0 + k;
            float a = RAW ? As_[ch] : p1[b * CIN + ch];
            float sf = RAW ? Ss_[ch] : p2[b * CIN + ch];
            float v = (y[(size_t)(n0 + r) * CIN + ch] - a) * sf + bnp[ch];
            if (RELU) v = fmaxf(v, 0.f);
            hs[r][k] = v;
        }
        __syncthreads();
        int k = 0;
        for (; k + 4 <= kc; k += 4) {
            float w0 = w1[(size_t)(k0 + k) * C + c];
            float w1v = w1[(size_t)(k0 + k + 1) * C + c];
            float w2v = w1[(size_t)(k0 + k + 2) * C + c];
            float w3v = w1[(size_t)(k0 + k + 3) * C + c];
            #pragma unroll
            for (int r = 0; r < ROWS; ++r) {
                f32x4 hv = *(const f32x4*)&hs[r][k];
                acc[r] = fmaf(hv[0], w0, acc[r]);
                acc[r] = fmaf(hv[1], w1v, acc[r]);
                acc[r] = fmaf(hv[2], w2v, acc[r]);
                acc[r] = fmaf(hv[3], w3v, acc[r]);
            }
        }
        for (; k < kc; ++k) {
            float wv = w1[(size_t)(k0 + k) * C + c];
            #pragma unroll
            for (int r = 0; r < ROWS; ++r)
                acc[r] = fmaf(hs[r][k], wv, acc[r]);
        }
    }
    float pacc[ROWS];
    #pragma unroll
    for (int r = 0; r < ROWS; ++r) pacc[r] = 0.f;
    #pragma unroll
    for (int e = 0; e < 3; ++e) {
        float wv = w1[(size_t)(CIN + e) * C + c];
        #pragma unroll
        for (int r = 0; r < ROWS; ++r)
            pacc[r] = fmaf(pos[(n0 + r) * 3 + e], wv, pacc[r]);
    }
    float bv = b1[c];
    #pragma unroll
    for (int r = 0; r < ROWS; ++r) {
        U[(size_t)(n0 + r) * C + c] = acc[r] + pacc[r] + bv;
        P[(size_t)(n0 + r) * C + c] = pacc[r];
    }
}

// ---------------- Edge MLP2 (small C): round-2 proven monolithic-stage kernel ----------------
template<int C, int W>
__global__ __launch_bounds__(W * 64, 4) void edge_kernel(const float* __restrict__ U, const float* __restrict__ P,
                                                         const int* __restrict__ knn, const unsigned short* __restrict__ w2t,
                                                         const float* __restrict__ b2, float* __restrict__ Y,
                                                         float* __restrict__ sum1, float* __restrict__ sum2) {
    constexpr int NCT = C / (W * 16);    // col tiles per wave
    constexpr int S32 = C / 32;          // k32 tiles
    constexpr int NCHUNK = C / 8;        // 16B chunks per row
    __shared__ unsigned short Th[64 * C];   // full message tile, swizzled
    __shared__ int jn[64];
    __shared__ float Pr[C];              // block-uniform dst-row of P
    const int bid = blockIdx.x;
    const int i = ((bid & 7) << 9) | (bid >> 3);   // XCD = bid%8 = graph(i): gather stays in one L2
    const int tid = threadIdx.x;
    const int wave = tid >> 6, lane = tid & 63, m = lane & 15, quad = lane >> 4;
    const int cw = wave * (NCT * 16);
    if (tid < 64) jn[tid] = knn[(size_t)i * KNN + tid];
    for (int idx = tid; idx < C; idx += W * 64) Pr[idx] = P[(size_t)i * C + idx];
    __syncthreads();                     // jn + Pr visible
    #pragma unroll 2
    for (int idx = tid; idx < 64 * NCHUNK; idx += W * 64) {
        int row = idx / NCHUNK, ch = idx - row * NCHUNK;
        const float* up = U + (size_t)jn[row] * C + ch * 8;
        f32x4 va = *(const f32x4*)up;
        f32x4 vb = *(const f32x4*)(up + 4);
        f32x4 pa = *(const f32x4*)&Pr[ch * 8];
        f32x4 pb = *(const f32x4*)&Pr[ch * 8 + 4];
        uint4 pk;
        pk.x = (unsigned)f2h(fmaxf(va[0] - pa[0], 0.f)) | ((unsigned)f2h(fmaxf(va[1] - pa[1], 0.f)) << 16);
        pk.y = (unsigned)f2h(fmaxf(va[2] - pa[2], 0.f)) | ((unsigned)f2h(fmaxf(va[3] - pa[3], 0.f)) << 16);
        pk.z = (unsigned)f2h(fmaxf(vb[0] - pb[0], 0.f)) | ((unsigned)f2h(fmaxf(vb[1] - pb[1], 0.f)) << 16);
        pk.w = (unsigned)f2h(fmaxf(vb[2] - pb[2], 0.f)) | ((unsigned)f2h(fmaxf(vb[3] - pb[3], 0.f)) << 16);
        int sc = (ch & ~7) | ((ch ^ row) & 7);
        *(uint4*)&Th[row * C + sc * 8] = pk;
    }
    __syncthreads();
    f32x4 acc[4][NCT];
    f32x4 zero = {0.f, 0.f, 0.f, 0.f};
    #pragma unroll
    for (int rt = 0; rt < 4; ++rt)
        #pragma unroll
        for (int ct = 0; ct < NCT; ++ct)
            acc[rt][ct] = zero;
    #pragma unroll 2
    for (int s = 0; s < S32; ++s) {
        f16x8 a[4];
        #pragma unroll
        for (int rt = 0; rt < 4; ++rt) {
            int row = rt * 16 + m;
            int chunk = s * 4 + quad;
            int sc = (chunk & ~7) | ((chunk ^ row) & 7);
            a[rt] = *(const f16x8*)&Th[row * C + sc * 8];
        }
        #pragma unroll
        for (int ct = 0; ct < NCT; ++ct) {
            const f16x8 bb = *(const f16x8*)(w2t +
                (size_t)(((cw >> 4) + ct) * S32 + s) * 512 + quad * 128 + m * 8);
            #pragma unroll
            for (int rt = 0; rt < 4; ++rt)
                acc[rt][ct] = __builtin_amdgcn_mfma_f32_16x16x32_f16(a[rt], bb, acc[rt][ct], 0, 0, 0);
        }
    }
    const int gb = i >> 9;
    #pragma unroll
    for (int ct = 0; ct < NCT; ++ct) {
        float vmax = -3.4e38f;
        #pragma unroll
        for (int rt = 0; rt < 4; ++rt) {
            vmax = fmaxf(vmax, acc[rt][ct][0]);
            vmax = fmaxf(vmax, acc[rt][ct][1]);
            vmax = fmaxf(vmax, acc[rt][ct][2]);
            vmax = fmaxf(vmax, acc[rt][ct][3]);
        }
        vmax = fmaxf(vmax, __shfl_xor(vmax, 16));
        vmax = fmaxf(vmax, __shfl_xor(vmax, 32));
        if (quad == 0) {
            int col = cw + ct * 16 + m;
            float val = vmax + b2[col];
            Y[(size_t)i * C + col] = val;
            atomicAdd(&sum1[gb * C + col], val);
            atomicAdd(&sum2[gb * C + col], val * val);
        }
    }
}

__device__ __forceinline__ uint4 pack8(f32x4 va, f32x4 vb, f32x4 pa, f32x4 pb) {
    uint4 pk;
    pk.x = (unsigned)f2h(fmaxf(va[0] - pa[0], 0.f)) | ((unsigned)f2h(fmaxf(va[1] - pa[1], 0.f)) << 16);
    pk.y = (unsigned)f2h(fmaxf(va[2] - pa[2], 0.f)) | ((unsigned)f2h(fmaxf(va[3] - pa[3], 0.f)) << 16);
    pk.z = (unsigned)f2h(fmaxf(vb[0] - pb[0], 0.f)) | ((unsigned)f2h(fmaxf(vb[1] - pb[1], 0.f)) << 16);
    pk.w = (unsigned)f2h(fmaxf(vb[2] - pb[2], 0.f)) | ((unsigned)f2h(fmaxf(vb[3] - pb[3], 0.f)) << 16);
    return pk;
}

// ---------------- Edge MLP2 (large C): round-9 proven best (146.4 us, 0 conflicts).
// 2 dst nodes (rt=8), barrier-free sweep, zero per-read address VALU (swizzle algebra folded
// into idx0/idx1 + linear tcur stride), 2-deep B register pipeline, setprio around MFMA bursts.
template<int C>
__global__ __launch_bounds__(512, 2) void edgeb_kernel(const float* __restrict__ U, const float* __restrict__ P,
                                                       const int* __restrict__ knn, const unsigned short* __restrict__ w2t,
                                                       const float* __restrict__ b2, float* __restrict__ Y,
                                                       float* __restrict__ sum1, float* __restrict__ sum2) {
    constexpr int NCT = C / 128;         // col tiles per wave (8 waves)
    constexpr int S32 = C / 32;          // k32 tiles total
    constexpr int NCHK = C / 8;          // 16B chunks per row
    constexpr int RSTEP = 512 / NCHK;    // staging rows per iteration
    __shared__ unsigned short Th[(C / 64) * 128 * 64];   // chunk-major swizzled A-tile
    __shared__ int jn[128];
    const int bid = blockIdx.x;
    const int g = bid & 7;               // XCD = graph: U/P/w2t stay in one L2
    const int n0 = (g << 9) | ((bid >> 3) << 1);   // first of 2 dst nodes
    const int tid = threadIdx.x;
    const int lane = tid & 63, wave = tid >> 6, m = lane & 15, quad = lane >> 4;
    const int cw = wave * (NCT * 16);
    if (tid < 128) jn[tid] = knn[(size_t)(n0 + (tid >> 6)) * KNN + (tid & 63)];
    // per-thread fixed staging columns -> P values in registers (loaded once, pre-barrier)
    const int ch = tid & (NCHK - 1);     // chunk 0..NCHK-1
    const int rb = tid / NCHK;           // staging row base
    const int cblk = ch >> 3, cw8 = ch & 7;
    const float* pp = P + (size_t)n0 * C + ch * 8;
    f32x4 pa0 = *(const f32x4*)pp;
    f32x4 pb0 = *(const f32x4*)(pp + 4);
    f32x4 pa1 = *(const f32x4*)(pp + C);
    f32x4 pb1 = *(const f32x4*)(pp + C + 4);
    __syncthreads();                     // jn visible
    // ---- stage all 128 rows x C cols as f16 messages (measured: 0 bank conflicts) ----
    #pragma unroll 4
    for (int t = 0; t < 128 / RSTEP; ++t) {
        int row = rb + t * RSTEP;
        const float* up = U + (size_t)jn[row] * C + ch * 8;
        f32x4 va = *(const f32x4*)up;
        f32x4 vb = *(const f32x4*)(up + 4);
        f32x4 pa = (row & 64) ? pa1 : pa0;
        f32x4 pb = (row & 64) ? pb1 : pb0;
        *(uint4*)&Th[cblk * 8192 + row * 64 + ((cw8 ^ (row & 7)) << 3)] = pack8(va, vb, pa, pb);
    }
    __syncthreads();
    // ---- barrier-free MFMA sweep, zero per-read address VALU ----
    f32x4 acc[8][NCT];
    f32x4 zero = {0.f, 0.f, 0.f, 0.f};
    #pragma unroll
    for (int rt = 0; rt < 8; ++rt)
        #pragma unroll
        for (int ct = 0; ct < NCT; ++ct)
            acc[rt][ct] = zero;
    const unsigned short* wt = w2t + (size_t)(cw >> 4) * S32 * 512 + quad * 128 + m * 8;
    int idx0[8], idx1[8];                // A-tile element indices for even/odd k32-step parity
    #pragma unroll
    for (int rt = 0; rt < 8; ++rt) {
        int row = rt * 16 + m;
        idx0[rt] = row * 64 + ((quad ^ (row & 7)) << 3);
        idx1[rt] = row * 64 + (((4 + quad) ^ (row & 7)) << 3);
    }
    const unsigned short* pB[NCT];       // next-prefetch B pointers (s+2 targets)
    #pragma unroll
    for (int ct = 0; ct < NCT; ++ct)
        pB[ct] = wt + ((size_t)ct * S32 + 2) * 512;
    f16x8 bbA[NCT], bbB[NCT];
    #pragma unroll
    for (int ct = 0; ct < NCT; ++ct) {
        bbA[ct] = *(const f16x8*)(wt + (size_t)ct * S32 * 512);
        bbB[ct] = *(const f16x8*)(wt + ((size_t)ct * S32 + 1) * 512);
    }
    const unsigned short* tcur = Th;     // = Th + (s>>1)*8192
    auto step = [&](f16x8 (&buf)[NCT], const int (&idx)[8], int poff, bool pre) {
        f16x8 a[8];
        #pragma unroll
        for (int rt = 0; rt < 8; ++rt)
            a[rt] = *(const f16x8*)&tcur[idx[rt]];
        #pragma unroll
        for (int ct = 0; ct < NCT; ++ct) {
            f16x8 bcur = buf[ct];
            if (pre) buf[ct] = *(const f16x8*)(pB[ct] + poff);
            __builtin_amdgcn_s_setprio(1);
            #pragma unroll
            for (int rt = 0; rt < 8; ++rt)
                acc[rt][ct] = __builtin_amdgcn_mfma_f32_16x16x32_f16(a[rt], bcur, acc[rt][ct], 0, 0, 0);
            __builtin_amdgcn_s_setprio(0);
        }
    };
    #pragma unroll 1
    for (int s = 0; s + 2 < S32; s += 2) {
        step(bbA, idx0, 0, true);        // consume s,   prefetch s+2
        step(bbB, idx1, 512, true);      // consume s+1, prefetch s+3
        tcur += 8192;
        #pragma unroll
        for (int ct = 0; ct < NCT; ++ct) pB[ct] += 1024;
    }
    step(bbA, idx0, 0, false);           // s = S32-2
    step(bbB, idx1, 0, false);           // s = S32-1
    // ---- epilogue: scatter-max per node half (node h = rt>>2) ----
    #pragma unroll
    for (int h = 0; h < 2; ++h) {
        #pragma unroll
        for (int ct = 0; ct < NCT; ++ct) {
            float vmax = -3.4e38f;
            #pragma unroll
            for (int rt = h * 4; rt < h * 4 + 4; ++rt) {
                vmax = fmaxf(vmax, acc[rt][ct][0]);
                vmax = fmaxf(vmax, acc[rt][ct][1]);
                vmax = fmaxf(vmax, acc[rt][ct][2]);
                vmax = fmaxf(vmax, acc[rt][ct][3]);
            }
            vmax = fmaxf(vmax, __shfl_xor(vmax, 16));
            vmax = fmaxf(vmax, __shfl_xor(vmax, 32));
            if (quad == 0) {
                int col = cw + ct * 16 + m;
                float val = vmax + b2[col];
                Y[(size_t)(n0 + h) * C + col] = val;
                atomicAdd(&sum1[g * C + col], val);
                atomicAdd(&sum2[g * C + col], val * val);
            }
        }
    }
}

// ---------------- Classifier with fused gn6 (stats from atomic sums) ----------------
__global__ __launch_bounds__(256) void cls_kernel(const float* __restrict__ y, const float* __restrict__ sum1,
                                                  const float* __restrict__ sum2, const float* __restrict__ ms,
                                                  const float* __restrict__ gw, const float* __restrict__ gnb,
                                                  const float* __restrict__ w, const float* __restrict__ bias,
                                                  float* __restrict__ out) {
    __shared__ float wl[512 * 14];      // 28672 B
    __shared__ _Float16 hn[16][520];    // 16640 B (pad 8 -> 2-way LDS aliasing only)
    __shared__ float As[512], Ss[512];  // 4096 B
    int tid = threadIdx.x;
    int n0 = blockIdx.x * 16;
    int b = n0 >> 9;
    for (int ch = tid; ch < 512; ch += 256) {
        float s1 = sum1[b * 512 + ch], s2 = sum2[b * 512 + ch];
        float mean = s1 * (1.f / NPTS);
        float a = mean * ms[ch];
        float var = s2 * (1.f / NPTS) - 2.f * a * mean + a * a;
        As[ch] = a;
        Ss[ch] = gw[ch] / sqrtf(var + EPSN);
    }
    for (int idx = tid; idx < 512 * 14; idx += 256) wl[idx] = w[idx];
    __syncthreads();
    for (int idx = tid; idx < 16 * 512; idx += 256) {
        int r = idx >> 9, k = idx & 511;
        float v = (y[(size_t)(n0 + r) * 512 + k] - As[k]) * Ss[k] + gnb[k];
        hn[r][k] = (_Float16)fmaxf(v, 0.f);
    }
    __syncthreads();
    if (tid < 224) {
        int nl = tid / 14, c = tid - nl * 14;
        float acc = bias[c];
        for (int k = 0; k < 512; ++k)
            acc += (float)hn[nl][k] * wl[k * 14 + c];
        out[(size_t)(n0 + nl) * 14 + c] = acc;
    }
}

extern "C" void kernel_launch(void* const* d_in, const int* in_sizes, int n_in,
                              void* d_out, int out_size, void* d_ws, size_t ws_size,
                              hipStream_t stream) {
    const float* pos = (const float*)d_in[0];
    const float* gnw[6]; const float* gnb[6]; const float* gnms[6];
    for (int i = 0; i < 6; ++i) {
        gnw[i]  = (const float*)d_in[2 + 3 * i];
        gnb[i]  = (const float*)d_in[3 + 3 * i];
        gnms[i] = (const float*)d_in[4 + 3 * i];
    }
    const float* cw1[5]; const float* cb1[5]; const float* cw2[5]; const float* cb2[5];
    for (int i = 0; i < 5; ++i) {
        cw1[i] = (const float*)d_in[20 + 4 * i];
        cb1[i] = (const float*)d_in[21 + 4 * i];
        cw2[i] = (const float*)d_in[22 + 4 * i];
        cb2[i] = (const float*)d_in[23 + 4 * i];
    }
    const float* clsw = (const float*)d_in[40];
    const float* clsb = (const float*)d_in[41];
    float* out = (float*)d_out;

    char* ws = (char*)d_ws;
    int* knn             = (int*)(ws + 0);                 // 1 MB
    float* U             = (float*)(ws + 1048576);         // 8 MB
    float* P             = (float*)(ws + 9437184);         // 8 MB
    float* y             = (float*)(ws + 26214400);        // 8 MB
    float* Aa            = (float*)(ws + 34603008);        // 16 KB
    float* Sa            = (float*)(ws + 34619392);        // 16 KB
    unsigned short* w2t0 = (unsigned short*)(ws + 34635776);  // 8 KB
    unsigned short* w2t1 = (unsigned short*)(ws + 34643968);  // 32 KB
    unsigned short* w2t2 = (unsigned short*)(ws + 34676736);  // 128 KB
    unsigned short* w2t3 = (unsigned short*)(ws + 34807808);  // 512 KB
    unsigned short* w2t4 = (unsigned short*)(ws + 35332096);  // 512 KB
    float* acc           = (float*)(ws + 35856384);           // 160 KB: 5 x (4096+4096) floats
    float* s1l[5]; float* s2l[5];
    for (int l = 0; l < 5; ++l) { s1l[l] = acc + l * 8192; s2l[l] = s1l[l] + 4096; }

    // setup: w2 conversions + stat-zero + gn1 stats + kNN
    setup_kernel<<<N_NODES, 64, 0, stream>>>(pos, knn, cw2[0], cw2[1], cw2[2], cw2[3], cw2[4],
                                             w2t0, w2t1, w2t2, w2t3, w2t4, acc,
                                             gnms[0], gnw[0], Aa, Sa);

    // Layer 1 (gn1 apply fused into node1, no relu)
    node_kernel<3, 64, 0, 0><<<N_NODES / 16, 64, 0, stream>>>(pos, pos, Aa, Sa, gnms[0], gnw[0], gnb[0], cw1[0], cb1[0], U, P);
    edge_kernel<64, 4><<<N_NODES, 256, 0, stream>>>(U, P, knn, w2t0, cb2[0], y, s1l[0], s2l[0]);

    // Layer 2 (stats from L1 edge atomics)
    node_kernel<64, 128, 1, 1><<<N_NODES / 16, 128, 0, stream>>>(y, pos, s1l[0], s2l[0], gnms[1], gnw[1], gnb[1], cw1[1], cb1[1], U, P);
    edge_kernel<128, 8><<<N_NODES, 512, 0, stream>>>(U, P, knn, w2t1, cb2[1], y, s1l[1], s2l[1]);

    // Layer 3
    node_kernel<128, 256, 1, 1><<<N_NODES / 16, 256, 0, stream>>>(y, pos, s1l[1], s2l[1], gnms[2], gnw[2], gnb[2], cw1[2], cb1[2], U, P);
    edgeb_kernel<256><<<N_NODES / 2, 512, 0, stream>>>(U, P, knn, w2t2, cb2[2], y, s1l[2], s2l[2]);

    // Layer 4
    node_kernel<256, 512, 1, 1><<<N_NODES / 16, 512, 0, stream>>>(y, pos, s1l[2], s2l[2], gnms[3], gnw[3], gnb[3], cw1[3], cb1[3], U, P);
    edgeb_kernel<512><<<N_NODES / 2, 512, 0, stream>>>(U, P, knn, w2t3, cb2[3], y, s1l[3], s2l[3]);

    // Layer 5
    node_kernel<512, 512, 1, 1><<<N_NODES / 16, 512, 0, stream>>>(y, pos, s1l[3], s2l[3], gnms[4], gnw[4], gnb[4], cw1[4], cb1[4], U, P);
    edgeb_kernel<512><<<N_NODES / 2, 512, 0, stream>>>(U, P, knn, w2t4, cb2[4], y, s1l[4], s2l[4]);

    // gn6 (stats from L5 edge atomics) fused into classifier
    cls_kernel<<<N_NODES / 16, 256, 0, stream>>>(y, s1l[4], s2l[4], gnms[5], gnw[5], gnb[5], clsw, clsb, out);
}

// Round 13
// 639.649 us; speedup vs baseline: 1.1445x; 1.0953x over previous
//
#include <hip/hip_runtime.h>
#include <stdint.h>

#define N_NODES 4096
#define NGRAPH 8
#define NPTS 512
#define KNN 64
#define EPSN 1e-5f

typedef _Float16 f16x8 __attribute__((ext_vector_type(8)));
typedef float f32x4 __attribute__((ext_vector_type(4)));
typedef unsigned long long u64;

__device__ __forceinline__ unsigned short f2h(float f) {
    _Float16 h = (_Float16)f;   // RNE, v_cvt_f16_f32
    union { _Float16 h; unsigned short u; } cv; cv.h = h;
    return cv.u;
}
__device__ __forceinline__ float h2f(unsigned short u) {
    union { unsigned short u; _Float16 h; } cv; cv.u = u;
    return (float)cv.h;
}

// Chunk-major w2 conversion: one thread -> one 16-half chunk (8 strided reads -> 1 coalesced 16B store).
__device__ __forceinline__ void w2cv8(const float* __restrict__ src, unsigned short* __restrict__ dst,
                                      int c, int lg2c) {
    int C = 1 << lg2c;
    int mm = c & 15, q = (c >> 4) & 3, F = c >> 6;
    int k5 = F & ((C >> 5) - 1), n4 = F >> (lg2c - 5);
    int n = n4 * 16 + mm, kb = k5 * 32 + q * 8;
    unsigned short h[8];
    #pragma unroll
    for (int t = 0; t < 8; ++t) h[t] = f2h(src[(size_t)(kb + t) * C + n]);
    uint4 pk;
    pk.x = (unsigned)h[0] | ((unsigned)h[1] << 16);
    pk.y = (unsigned)h[2] | ((unsigned)h[3] << 16);
    pk.z = (unsigned)h[4] | ((unsigned)h[5] << 16);
    pk.w = (unsigned)h[6] | ((unsigned)h[7] << 16);
    *(uint4*)&dst[(size_t)c * 8] = pk;
}

// w1 hi/lo converter for Markidis MFMA node (K x 512, K != C aware: F = n4*(K/32) + k5).
// kl = log2(K/32). Output layout identical to w2t read pattern with S32 = K/32.
__device__ __forceinline__ void w1cv8hl(const float* __restrict__ src, unsigned short* __restrict__ dh,
                                        unsigned short* __restrict__ dl, int c, int kl) {
    int mm = c & 15, q = (c >> 4) & 3, F = c >> 6;
    int k5 = F & ((1 << kl) - 1), n4 = F >> kl;
    int n = n4 * 16 + mm, kb = k5 * 32 + q * 8;
    unsigned short hh[8], ll[8];
    #pragma unroll
    for (int t = 0; t < 8; ++t) {
        float v = src[(size_t)(kb + t) * 512 + n];
        hh[t] = f2h(v);
        ll[t] = f2h(v - h2f(hh[t]));
    }
    uint4 ph, pl;
    ph.x = (unsigned)hh[0] | ((unsigned)hh[1] << 16);
    ph.y = (unsigned)hh[2] | ((unsigned)hh[3] << 16);
    ph.z = (unsigned)hh[4] | ((unsigned)hh[5] << 16);
    ph.w = (unsigned)hh[6] | ((unsigned)hh[7] << 16);
    pl.x = (unsigned)ll[0] | ((unsigned)ll[1] << 16);
    pl.y = (unsigned)ll[2] | ((unsigned)ll[3] << 16);
    pl.z = (unsigned)ll[4] | ((unsigned)ll[5] << 16);
    pl.w = (unsigned)ll[6] | ((unsigned)ll[7] << 16);
    *(uint4*)&dh[(size_t)c * 8] = ph;
    *(uint4*)&dl[(size_t)c * 8] = pl;
}

// ---------------- setup: w2/w1 conversions + stat-zero + gn1 stats + kNN, one dispatch ----------------
__global__ __launch_bounds__(64) void setup_kernel(const float* __restrict__ pos, int* __restrict__ knn_out,
                                                   const float* __restrict__ wa, const float* __restrict__ wb,
                                                   const float* __restrict__ wc, const float* __restrict__ wd,
                                                   const float* __restrict__ we,
                                                   const float* __restrict__ w14, const float* __restrict__ w15,
                                                   unsigned short* __restrict__ oa, unsigned short* __restrict__ ob,
                                                   unsigned short* __restrict__ oc, unsigned short* __restrict__ od,
                                                   unsigned short* __restrict__ oe,
                                                   unsigned short* __restrict__ o14h, unsigned short* __restrict__ o14l,
                                                   unsigned short* __restrict__ o15h, unsigned short* __restrict__ o15l,
                                                   float* __restrict__ statz,
                                                   const float* __restrict__ ms1, const float* __restrict__ gw1,
                                                   float* __restrict__ Aa, float* __restrict__ Sa) {
#pragma clang fp contract(off)
    __shared__ float px[NPTS], py[NPTS], pz[NPTS];
    __shared__ u64 keys[NPTS];
    int bid = blockIdx.x;
    int tid = threadIdx.x;   // 0..63
    int gidx = bid * 64 + tid;           // 0..262143
    for (int idx = gidx; idx < 40960; idx += 262144) statz[idx] = 0.f;
    // conversions: w2 chunks [0,76288); w1 L4 hi/lo [76288,92672); w1 L5 hi/lo [92672,125440)
    if (gidx < 125440) {
        int c = gidx;
        if (c < 512)         w2cv8(wa, oa, c, 6);
        else if (c < 2560)   w2cv8(wb, ob, c - 512, 7);
        else if (c < 10752)  w2cv8(wc, oc, c - 2560, 8);
        else if (c < 43520)  w2cv8(wd, od, c - 10752, 9);
        else if (c < 76288)  w2cv8(we, oe, c - 43520, 9);
        else if (c < 92672)  w1cv8hl(w14, o14h, o14l, c - 76288, 3);   // K=256
        else                 w1cv8hl(w15, o15h, o15l, c - 92672, 4);   // K=512
    }
    if (bid < 24) {   // gn1 stats: 24 (graph,channel) wave-jobs
        int g = bid / 3, ch = bid - g * 3;
        float s1 = 0.f, s2 = 0.f;
        for (int n = tid; n < NPTS; n += 64) {
            float v = pos[(g * NPTS + n) * 3 + ch];
            s1 += v; s2 += v * v;
        }
        #pragma unroll
        for (int off = 32; off; off >>= 1) { s1 += __shfl_xor(s1, off); s2 += __shfl_xor(s2, off); }
        if (tid == 0) {
            float mean = s1 * (1.f / NPTS);
            float av = mean * ms1[ch];
            float var = s2 * (1.f / NPTS) - 2.f * av * mean + av * av;
            Aa[g * 3 + ch] = av;
            Sa[g * 3 + ch] = gw1[ch] / sqrtf(var + EPSN);
        }
    }
    // ---- kNN: 1-wave bitonic sort of this dst point's 512 keys ----
    int b = bid >> 9;
    int il = bid & (NPTS - 1);
    for (int n = tid; n < NPTS; n += 64) {
        int base = (b * NPTS + n) * 3;
        px[n] = pos[base]; py[n] = pos[base + 1]; pz[n] = pos[base + 2];
    }
    __syncthreads();
    float xi = px[il], yi = py[il], zi = pz[il];
    for (int n = tid; n < NPTS; n += 64) {
        float dx = px[n] - xi, dy = py[n] - yi, dz = pz[n] - zi;
        float d2 = dx * dx;
        d2 = d2 + dy * dy;
        d2 = d2 + dz * dz;
        keys[n] = (((u64)__float_as_uint(d2)) << 32) | (unsigned)n;
    }
    __syncthreads();
    for (int k2 = 2; k2 <= NPTS; k2 <<= 1) {
        for (int j = k2 >> 1; j > 0; j >>= 1) {
            #pragma unroll 4
            for (int p = 0; p < 4; ++p) {
                int pid = tid + p * 64;
                int t = ((pid & ~(j - 1)) << 1) | (pid & (j - 1));
                int ixj = t | j;
                u64 a = keys[t], c = keys[ixj];
                bool up = ((t & k2) == 0);
                if ((a > c) == up) { keys[t] = c; keys[ixj] = a; }
            }
            __syncthreads();
        }
    }
    int j0 = (int)(keys[tid] & 0xffffffffu);
    knn_out[(size_t)(b * NPTS + il) * KNN + tid] = b * NPTS + j0;
}

// ---------------- Per-node MLP1 (scalar path, layers 1-3) ----------------
template<int CIN, int C, int RELU, int RAW>
__global__ __launch_bounds__(C) void node_kernel(const float* __restrict__ y, const float* __restrict__ pos,
                                                 const float* __restrict__ p1, const float* __restrict__ p2,
                                                 const float* __restrict__ ms, const float* __restrict__ gw,
                                                 const float* __restrict__ bnp,
                                                 const float* __restrict__ w1, const float* __restrict__ b1,
                                                 float* __restrict__ U, float* __restrict__ P) {
    constexpr int ROWS = 16;
    constexpr int KC = 64;
    constexpr int LDH = KC + 4;
    __shared__ float hs[ROWS][LDH];   // 4352 B
    __shared__ float As_[CIN > 0 ? CIN : 1], Ss_[CIN > 0 ? CIN : 1];
    const int c = threadIdx.x;
    const int n0 = blockIdx.x * ROWS;
    const int b = n0 >> 9;            // all 16 rows in one graph
    if (RAW) {
        for (int ch = c; ch < CIN; ch += C) {
            float s1 = p1[b * CIN + ch], s2 = p2[b * CIN + ch];
            float mean = s1 * (1.f / NPTS);
            float a = mean * ms[ch];
            float var = s2 * (1.f / NPTS) - 2.f * a * mean + a * a;
            As_[ch] = a;
            Ss_[ch] = gw[ch] / sqrtf(var + EPSN);
        }
    }
    float acc[ROWS];
    #pragma unroll
    for (int r = 0; r < ROWS; ++r) acc[r] = 0.f;
    constexpr int NCHUNK = (CIN + KC - 1) / KC;
    #pragma unroll 1
    for (int s = 0; s < NCHUNK; ++s) {
        const int k0 = s * KC;
        const int kc = (CIN - k0 < KC) ? (CIN - k0) : KC;
        __syncthreads();
        for (int idx = c; idx < ROWS * kc; idx += C) {
            int r = idx / kc, k = idx - r * kc;
            int ch = k0 + k;
            float a = RAW ? As_[ch] : p1[b * CIN + ch];
            float sf = RAW ? Ss_[ch] : p2[b * CIN + ch];
            float v = (y[(size_t)(n0 + r) * CIN + ch] - a) * sf + bnp[ch];
            if (RELU) v = fmaxf(v, 0.f);
            hs[r][k] = v;
        }
        __syncthreads();
        int k = 0;
        for (; k + 4 <= kc; k += 4) {
            float w0 = w1[(size_t)(k0 + k) * C + c];
            float w1v = w1[(size_t)(k0 + k + 1) * C + c];
            float w2v = w1[(size_t)(k0 + k + 2) * C + c];
            float w3v = w1[(size_t)(k0 + k + 3) * C + c];
            #pragma unroll
            for (int r = 0; r < ROWS; ++r) {
                f32x4 hv = *(const f32x4*)&hs[r][k];
                acc[r] = fmaf(hv[0], w0, acc[r]);
                acc[r] = fmaf(hv[1], w1v, acc[r]);
                acc[r] = fmaf(hv[2], w2v, acc[r]);
                acc[r] = fmaf(hv[3], w3v, acc[r]);
            }
        }
        for (; k < kc; ++k) {
            float wv = w1[(size_t)(k0 + k) * C + c];
            #pragma unroll
            for (int r = 0; r < ROWS; ++r)
                acc[r] = fmaf(hs[r][k], wv, acc[r]);
        }
    }
    float pacc[ROWS];
    #pragma unroll
    for (int r = 0; r < ROWS; ++r) pacc[r] = 0.f;
    #pragma unroll
    for (int e = 0; e < 3; ++e) {
        float wv = w1[(size_t)(CIN + e) * C + c];
        #pragma unroll
        for (int r = 0; r < ROWS; ++r)
            pacc[r] = fmaf(pos[(n0 + r) * 3 + e], wv, pacc[r]);
    }
    float bv = b1[c];
    #pragma unroll
    for (int r = 0; r < ROWS; ++r) {
        U[(size_t)(n0 + r) * C + c] = acc[r] + pacc[r] + bv;
        P[(size_t)(n0 + r) * C + c] = pacc[r];
    }
}

// ---------------- Per-node MLP1 via Markidis f16 hi/lo MFMA (layers 4-5, C=512) ----------------
// h@w1 = Ah*Bh + Al*Bh + Ah*Bl (f32 accumulate) -> error ~2^-22 relative, far below the f16
// message rounding already in the pipeline (absmax must stay exactly 0.046875).
// pos-part and bias stay exact f32 so U - P cancellation is bit-identical to before.
template<int CIN>
__global__ __launch_bounds__(512) void nodem_kernel(const float* __restrict__ y, const float* __restrict__ pos,
                                                    const float* __restrict__ p1, const float* __restrict__ p2,
                                                    const float* __restrict__ ms, const float* __restrict__ gw,
                                                    const float* __restrict__ bnp,
                                                    const unsigned short* __restrict__ w1h,
                                                    const unsigned short* __restrict__ w1l,
                                                    const float* __restrict__ w1s, const float* __restrict__ b1,
                                                    float* __restrict__ U, float* __restrict__ P) {
    constexpr int S32 = CIN / 32;
    constexpr int NCHR = CIN / 8;          // 16B chunks per row
    __shared__ unsigned short Ah[16 * CIN], Al[16 * CIN];
    __shared__ float As_[CIN], Ss_[CIN], pf[48];
    const int tid = threadIdx.x;
    const int n0 = blockIdx.x * 16;
    const int b = n0 >> 9;
    for (int ch = tid; ch < CIN; ch += 512) {
        float s1 = p1[b * CIN + ch], s2 = p2[b * CIN + ch];
        float mean = s1 * (1.f / NPTS);
        float a = mean * ms[ch];
        float var = s2 * (1.f / NPTS) - 2.f * a * mean + a * a;
        As_[ch] = a;
        Ss_[ch] = gw[ch] / sqrtf(var + EPSN);
    }
    if (tid < 48) pf[tid] = pos[n0 * 3 + tid];
    __syncthreads();
    // stage A (16 rows x CIN) as hi/lo f16, chunk-XOR swizzled (proven edge pattern)
    for (int ci = tid; ci < 2 * CIN; ci += 512) {
        int r = ci / NCHR, ch = ci - r * NCHR;
        int k0 = ch * 8;
        const float* yy = y + (size_t)(n0 + r) * CIN + k0;
        unsigned short hh[8], ll[8];
        #pragma unroll
        for (int t = 0; t < 8; ++t) {
            float v = (yy[t] - As_[k0 + t]) * Ss_[k0 + t] + bnp[k0 + t];
            v = fmaxf(v, 0.f);
            hh[t] = f2h(v);
            ll[t] = f2h(v - h2f(hh[t]));
        }
        int sc = (ch & ~7) | ((ch ^ r) & 7);
        uint4 ph, pl;
        ph.x = (unsigned)hh[0] | ((unsigned)hh[1] << 16);
        ph.y = (unsigned)hh[2] | ((unsigned)hh[3] << 16);
        ph.z = (unsigned)hh[4] | ((unsigned)hh[5] << 16);
        ph.w = (unsigned)hh[6] | ((unsigned)hh[7] << 16);
        pl.x = (unsigned)ll[0] | ((unsigned)ll[1] << 16);
        pl.y = (unsigned)ll[2] | ((unsigned)ll[3] << 16);
        pl.z = (unsigned)ll[4] | ((unsigned)ll[5] << 16);
        pl.w = (unsigned)ll[6] | ((unsigned)ll[7] << 16);
        *(uint4*)&Ah[r * CIN + sc * 8] = ph;
        *(uint4*)&Al[r * CIN + sc * 8] = pl;
    }
    __syncthreads();
    const int lane = tid & 63, wave = tid >> 6, m = lane & 15, quad = lane >> 4;
    const int cw = wave * 64;              // 4 col-tiles per wave, 8 waves cover 512
    f32x4 acc[4];
    f32x4 zero = {0.f, 0.f, 0.f, 0.f};
    #pragma unroll
    for (int ct = 0; ct < 4; ++ct) acc[ct] = zero;
    const unsigned short* bh = w1h + (size_t)(cw >> 4) * S32 * 512 + quad * 128 + m * 8;
    const unsigned short* bl = w1l + (size_t)(cw >> 4) * S32 * 512 + quad * 128 + m * 8;
    #pragma unroll 2
    for (int s = 0; s < S32; ++s) {
        int ci = s * 4 + quad;
        int sc = (ci & ~7) | ((ci ^ m) & 7);
        f16x8 aH = *(const f16x8*)&Ah[m * CIN + sc * 8];
        f16x8 aL = *(const f16x8*)&Al[m * CIN + sc * 8];
        #pragma unroll
        for (int ct = 0; ct < 4; ++ct) {
            f16x8 bH = *(const f16x8*)(bh + ((size_t)ct * S32 + s) * 512);
            f16x8 bL = *(const f16x8*)(bl + ((size_t)ct * S32 + s) * 512);
            acc[ct] = __builtin_amdgcn_mfma_f32_16x16x32_f16(aH, bH, acc[ct], 0, 0, 0);
            acc[ct] = __builtin_amdgcn_mfma_f32_16x16x32_f16(aL, bH, acc[ct], 0, 0, 0);
            acc[ct] = __builtin_amdgcn_mfma_f32_16x16x32_f16(aH, bL, acc[ct], 0, 0, 0);
        }
    }
    // epilogue: C/D layout col=lane&15, row=quad*4+reg (verified). pos-part + bias exact f32.
    #pragma unroll
    for (int ct = 0; ct < 4; ++ct) {
        int col = cw + ct * 16 + m;
        float w0 = w1s[(size_t)CIN * 512 + col];
        float w1v = w1s[(size_t)(CIN + 1) * 512 + col];
        float w2v = w1s[(size_t)(CIN + 2) * 512 + col];
        float bc = b1[col];
        #pragma unroll
        for (int j = 0; j < 4; ++j) {
            int r = quad * 4 + j;
            float pp = pf[r * 3] * w0;
            pp = fmaf(pf[r * 3 + 1], w1v, pp);
            pp = fmaf(pf[r * 3 + 2], w2v, pp);
            float val = acc[ct][j] + pp + bc;
            U[(size_t)(n0 + r) * 512 + col] = val;
            P[(size_t)(n0 + r) * 512 + col] = pp;
        }
    }
}

// ---------------- Edge MLP2 (small C): round-2 proven monolithic-stage kernel ----------------
template<int C, int W>
__global__ __launch_bounds__(W * 64, 4) void edge_kernel(const float* __restrict__ U, const float* __restrict__ P,
                                                         const int* __restrict__ knn, const unsigned short* __restrict__ w2t,
                                                         const float* __restrict__ b2, float* __restrict__ Y,
                                                         float* __restrict__ sum1, float* __restrict__ sum2) {
    constexpr int NCT = C / (W * 16);    // col tiles per wave
    constexpr int S32 = C / 32;          // k32 tiles
    constexpr int NCHUNK = C / 8;        // 16B chunks per row
    __shared__ unsigned short Th[64 * C];   // full message tile, swizzled
    __shared__ int jn[64];
    __shared__ float Pr[C];              // block-uniform dst-row of P
    const int bid = blockIdx.x;
    const int i = ((bid & 7) << 9) | (bid >> 3);   // XCD = bid%8 = graph(i): gather stays in one L2
    const int tid = threadIdx.x;
    const int wave = tid >> 6, lane = tid & 63, m = lane & 15, quad = lane >> 4;
    const int cw = wave * (NCT * 16);
    if (tid < 64) jn[tid] = knn[(size_t)i * KNN + tid];
    for (int idx = tid; idx < C; idx += W * 64) Pr[idx] = P[(size_t)i * C + idx];
    __syncthreads();                     // jn + Pr visible
    #pragma unroll 2
    for (int idx = tid; idx < 64 * NCHUNK; idx += W * 64) {
        int row = idx / NCHUNK, ch = idx - row * NCHUNK;
        const float* up = U + (size_t)jn[row] * C + ch * 8;
        f32x4 va = *(const f32x4*)up;
        f32x4 vb = *(const f32x4*)(up + 4);
        f32x4 pa = *(const f32x4*)&Pr[ch * 8];
        f32x4 pb = *(const f32x4*)&Pr[ch * 8 + 4];
        uint4 pk;
        pk.x = (unsigned)f2h(fmaxf(va[0] - pa[0], 0.f)) | ((unsigned)f2h(fmaxf(va[1] - pa[1], 0.f)) << 16);
        pk.y = (unsigned)f2h(fmaxf(va[2] - pa[2], 0.f)) | ((unsigned)f2h(fmaxf(va[3] - pa[3], 0.f)) << 16);
        pk.z = (unsigned)f2h(fmaxf(vb[0] - pb[0], 0.f)) | ((unsigned)f2h(fmaxf(vb[1] - pb[1], 0.f)) << 16);
        pk.w = (unsigned)f2h(fmaxf(vb[2] - pb[2], 0.f)) | ((unsigned)f2h(fmaxf(vb[3] - pb[3], 0.f)) << 16);
        int sc = (ch & ~7) | ((ch ^ row) & 7);
        *(uint4*)&Th[row * C + sc * 8] = pk;
    }
    __syncthreads();
    f32x4 acc[4][NCT];
    f32x4 zero = {0.f, 0.f, 0.f, 0.f};
    #pragma unroll
    for (int rt = 0; rt < 4; ++rt)
        #pragma unroll
        for (int ct = 0; ct < NCT; ++ct)
            acc[rt][ct] = zero;
    #pragma unroll 2
    for (int s = 0; s < S32; ++s) {
        f16x8 a[4];
        #pragma unroll
        for (int rt = 0; rt < 4; ++rt) {
            int row = rt * 16 + m;
            int chunk = s * 4 + quad;
            int sc = (chunk & ~7) | ((chunk ^ row) & 7);
            a[rt] = *(const f16x8*)&Th[row * C + sc * 8];
        }
        #pragma unroll
        for (int ct = 0; ct < NCT; ++ct) {
            const f16x8 bb = *(const f16x8*)(w2t +
                (size_t)(((cw >> 4) + ct) * S32 + s) * 512 + quad * 128 + m * 8);
            #pragma unroll
            for (int rt = 0; rt < 4; ++rt)
                acc[rt][ct] = __builtin_amdgcn_mfma_f32_16x16x32_f16(a[rt], bb, acc[rt][ct], 0, 0, 0);
        }
    }
    const int gb = i >> 9;
    #pragma unroll
    for (int ct = 0; ct < NCT; ++ct) {
        float vmax = -3.4e38f;
        #pragma unroll
        for (int rt = 0; rt < 4; ++rt) {
            vmax = fmaxf(vmax, acc[rt][ct][0]);
            vmax = fmaxf(vmax, acc[rt][ct][1]);
            vmax = fmaxf(vmax, acc[rt][ct][2]);
            vmax = fmaxf(vmax, acc[rt][ct][3]);
        }
        vmax = fmaxf(vmax, __shfl_xor(vmax, 16));
        vmax = fmaxf(vmax, __shfl_xor(vmax, 32));
        if (quad == 0) {
            int col = cw + ct * 16 + m;
            float val = vmax + b2[col];
            Y[(size_t)i * C + col] = val;
            atomicAdd(&sum1[gb * C + col], val);
            atomicAdd(&sum2[gb * C + col], val * val);
        }
    }
}

__device__ __forceinline__ uint4 pack8(f32x4 va, f32x4 vb, f32x4 pa, f32x4 pb) {
    uint4 pk;
    pk.x = (unsigned)f2h(fmaxf(va[0] - pa[0], 0.f)) | ((unsigned)f2h(fmaxf(va[1] - pa[1], 0.f)) << 16);
    pk.y = (unsigned)f2h(fmaxf(va[2] - pa[2], 0.f)) | ((unsigned)f2h(fmaxf(va[3] - pa[3], 0.f)) << 16);
    pk.z = (unsigned)f2h(fmaxf(vb[0] - pb[0], 0.f)) | ((unsigned)f2h(fmaxf(vb[1] - pb[1], 0.f)) << 16);
    pk.w = (unsigned)f2h(fmaxf(vb[2] - pb[2], 0.f)) | ((unsigned)f2h(fmaxf(vb[3] - pb[3], 0.f)) << 16);
    return pk;
}

// ---------------- Edge MLP2 (large C): round-9 structure, W-parameterized.
// C=512,W=8: unchanged best config (1 block/CU). C=256,W=4: 66 KB LDS + 4-wave blocks
// -> 2 resident blocks/CU (reg tier 2 waves/SIMD) so stage/sweep anti-phase across blocks.
template<int C, int W>
__global__ __launch_bounds__(W * 64, 2) void edgeb_kernel(const float* __restrict__ U, const float* __restrict__ P,
                                                          const int* __restrict__ knn, const unsigned short* __restrict__ w2t,
                                                          const float* __restrict__ b2, float* __restrict__ Y,
                                                          float* __restrict__ sum1, float* __restrict__ sum2) {
    constexpr int NCT = C / (W * 16);    // col tiles per wave (=4 for both configs)
    constexpr int S32 = C / 32;          // k32 tiles total
    constexpr int NCHK = C / 8;          // 16B chunks per row
    constexpr int RSTEP = (W * 64) / NCHK;   // staging rows per pass (=8 both)
    __shared__ unsigned short Th[(C / 64) * 128 * 64];   // chunk-major swizzled A-tile
    __shared__ int jn[128];
    const int bid = blockIdx.x;
    const int g = bid & 7;               // XCD = graph: U/P/w2t stay in one L2
    const int n0 = (g << 9) | ((bid >> 3) << 1);   // first of 2 dst nodes
    const int tid = threadIdx.x;
    const int lane = tid & 63, wave = tid >> 6, m = lane & 15, quad = lane >> 4;
    const int cw = wave * (NCT * 16);
    if (tid < 128) jn[tid] = knn[(size_t)(n0 + (tid >> 6)) * KNN + (tid & 63)];
    // per-thread fixed staging columns -> P values in registers (loaded once, pre-barrier)
    const int ch = tid & (NCHK - 1);     // chunk 0..NCHK-1
    const int rb = tid / NCHK;           // staging row base
    const int cblk = ch >> 3, cw8 = ch & 7;
    const float* pp = P + (size_t)n0 * C + ch * 8;
    f32x4 pa0 = *(const f32x4*)pp;
    f32x4 pb0 = *(const f32x4*)(pp + 4);
    f32x4 pa1 = *(const f32x4*)(pp + C);
    f32x4 pb1 = *(const f32x4*)(pp + C + 4);
    __syncthreads();                     // jn visible
    // ---- stage all 128 rows x C cols as f16 messages (measured: 0 bank conflicts) ----
    #pragma unroll 4
    for (int t = 0; t < 128 / RSTEP; ++t) {
        int row = rb + t * RSTEP;
        const float* up = U + (size_t)jn[row] * C + ch * 8;
        f32x4 va = *(const f32x4*)up;
        f32x4 vb = *(const f32x4*)(up + 4);
        f32x4 pa = (row & 64) ? pa1 : pa0;
        f32x4 pb = (row & 64) ? pb1 : pb0;
        *(uint4*)&Th[cblk * 8192 + row * 64 + ((cw8 ^ (row & 7)) << 3)] = pack8(va, vb, pa, pb);
    }
    __syncthreads();
    // ---- barrier-free MFMA sweep, zero per-read address VALU ----
    f32x4 acc[8][NCT];
    f32x4 zero = {0.f, 0.f, 0.f, 0.f};
    #pragma unroll
    for (int rt = 0; rt < 8; ++rt)
        #pragma unroll
        for (int ct = 0; ct < NCT; ++ct)
            acc[rt][ct] = zero;
    const unsigned short* wt = w2t + (size_t)(cw >> 4) * S32 * 512 + quad * 128 + m * 8;
    int idx0[8], idx1[8];                // A-tile element indices for even/odd k32-step parity
    #pragma unroll
    for (int rt = 0; rt < 8; ++rt) {
        int row = rt * 16 + m;
        idx0[rt] = row * 64 + ((quad ^ (row & 7)) << 3);
        idx1[rt] = row * 64 + (((4 + quad) ^ (row & 7)) << 3);
    }
    const unsigned short* pB[NCT];       // next-prefetch B pointers (s+2 targets)
    #pragma unroll
    for (int ct = 0; ct < NCT; ++ct)
        pB[ct] = wt + ((size_t)ct * S32 + 2) * 512;
    f16x8 bbA[NCT], bbB[NCT];
    #pragma unroll
    for (int ct = 0; ct < NCT; ++ct) {
        bbA[ct] = *(const f16x8*)(wt + (size_t)ct * S32 * 512);
        bbB[ct] = *(const f16x8*)(wt + ((size_t)ct * S32 + 1) * 512);
    }
    const unsigned short* tcur = Th;     // = Th + (s>>1)*8192
    auto step = [&](f16x8 (&buf)[NCT], const int (&idx)[8], int poff, bool pre) {
        f16x8 a[8];
        #pragma unroll
        for (int rt = 0; rt < 8; ++rt)
            a[rt] = *(const f16x8*)&tcur[idx[rt]];
        #pragma unroll
        for (int ct = 0; ct < NCT; ++ct) {
            f16x8 bcur = buf[ct];
            if (pre) buf[ct] = *(const f16x8*)(pB[ct] + poff);
            __builtin_amdgcn_s_setprio(1);
            #pragma unroll
            for (int rt = 0; rt < 8; ++rt)
                acc[rt][ct] = __builtin_amdgcn_mfma_f32_16x16x32_f16(a[rt], bcur, acc[rt][ct], 0, 0, 0);
            __builtin_amdgcn_s_setprio(0);
        }
    };
    #pragma unroll 1
    for (int s = 0; s + 2 < S32; s += 2) {
        step(bbA, idx0, 0, true);        // consume s,   prefetch s+2
        step(bbB, idx1, 512, true);      // consume s+1, prefetch s+3
        tcur += 8192;
        #pragma unroll
        for (int ct = 0; ct < NCT; ++ct) pB[ct] += 1024;
    }
    step(bbA, idx0, 0, false);           // s = S32-2
    step(bbB, idx1, 0, false);           // s = S32-1
    // ---- epilogue: scatter-max per node half (node h = rt>>2) ----
    #pragma unroll
    for (int h = 0; h < 2; ++h) {
        #pragma unroll
        for (int ct = 0; ct < NCT; ++ct) {
            float vmax = -3.4e38f;
            #pragma unroll
            for (int rt = h * 4; rt < h * 4 + 4; ++rt) {
                vmax = fmaxf(vmax, acc[rt][ct][0]);
                vmax = fmaxf(vmax, acc[rt][ct][1]);
                vmax = fmaxf(vmax, acc[rt][ct][2]);
                vmax = fmaxf(vmax, acc[rt][ct][3]);
            }
            vmax = fmaxf(vmax, __shfl_xor(vmax, 16));
            vmax = fmaxf(vmax, __shfl_xor(vmax, 32));
            if (quad == 0) {
                int col = cw + ct * 16 + m;
                float val = vmax + b2[col];
                Y[(size_t)(n0 + h) * C + col] = val;
                atomicAdd(&sum1[g * C + col], val);
                atomicAdd(&sum2[g * C + col], val * val);
            }
        }
    }
}

// ---------------- Classifier with fused gn6 (stats from atomic sums) ----------------
__global__ __launch_bounds__(256) void cls_kernel(const float* __restrict__ y, const float* __restrict__ sum1,
                                                  const float* __restrict__ sum2, const float* __restrict__ ms,
                                                  const float* __restrict__ gw, const float* __restrict__ gnb,
                                                  const float* __restrict__ w, const float* __restrict__ bias,
                                                  float* __restrict__ out) {
    __shared__ float wl[512 * 14];      // 28672 B
    __shared__ _Float16 hn[16][520];    // 16640 B (pad 8 -> 2-way LDS aliasing only)
    __shared__ float As[512], Ss[512];  // 4096 B
    int tid = threadIdx.x;
    int n0 = blockIdx.x * 16;
    int b = n0 >> 9;
    for (int ch = tid; ch < 512; ch += 256) {
        float s1 = sum1[b * 512 + ch], s2 = sum2[b * 512 + ch];
        float mean = s1 * (1.f / NPTS);
        float a = mean * ms[ch];
        float var = s2 * (1.f / NPTS) - 2.f * a * mean + a * a;
        As[ch] = a;
        Ss[ch] = gw[ch] / sqrtf(var + EPSN);
    }
    for (int idx = tid; idx < 512 * 14; idx += 256) wl[idx] = w[idx];
    __syncthreads();
    for (int idx = tid; idx < 16 * 512; idx += 256) {
        int r = idx >> 9, k = idx & 511;
        float v = (y[(size_t)(n0 + r) * 512 + k] - As[k]) * Ss[k] + gnb[k];
        hn[r][k] = (_Float16)fmaxf(v, 0.f);
    }
    __syncthreads();
    if (tid < 224) {
        int nl = tid / 14, c = tid - nl * 14;
        float acc = bias[c];
        for (int k = 0; k < 512; ++k)
            acc += (float)hn[nl][k] * wl[k * 14 + c];
        out[(size_t)(n0 + nl) * 14 + c] = acc;
    }
}

extern "C" void kernel_launch(void* const* d_in, const int* in_sizes, int n_in,
                              void* d_out, int out_size, void* d_ws, size_t ws_size,
                              hipStream_t stream) {
    const float* pos = (const float*)d_in[0];
    const float* gnw[6]; const float* gnb[6]; const float* gnms[6];
    for (int i = 0; i < 6; ++i) {
        gnw[i]  = (const float*)d_in[2 + 3 * i];
        gnb[i]  = (const float*)d_in[3 + 3 * i];
        gnms[i] = (const float*)d_in[4 + 3 * i];
    }
    const float* cw1[5]; const float* cb1[5]; const float* cw2[5]; const float* cb2[5];
    for (int i = 0; i < 5; ++i) {
        cw1[i] = (const float*)d_in[20 + 4 * i];
        cb1[i] = (const float*)d_in[21 + 4 * i];
        cw2[i] = (const float*)d_in[22 + 4 * i];
        cb2[i] = (const float*)d_in[23 + 4 * i];
    }
    const float* clsw = (const float*)d_in[40];
    const float* clsb = (const float*)d_in[41];
    float* out = (float*)d_out;

    char* ws = (char*)d_ws;
    int* knn             = (int*)(ws + 0);                 // 1 MB
    float* U             = (float*)(ws + 1048576);         // 8 MB
    float* P             = (float*)(ws + 9437184);         // 8 MB
    unsigned short* w1h4 = (unsigned short*)(ws + 17825792);  // 256 KB (in gap before y)
    unsigned short* w1l4 = (unsigned short*)(ws + 18088036 - 100);  // placed below via fixed offsets
    // use clean fixed offsets:
    w1h4                 = (unsigned short*)(ws + 17825792);  // 262144 B
    unsigned short* w1l4b= (unsigned short*)(ws + 18087936);  // 262144 B
    unsigned short* w1h5 = (unsigned short*)(ws + 18350080);  // 524288 B
    unsigned short* w1l5 = (unsigned short*)(ws + 18874368);  // 524288 B -> ends 19398656 < 26214400
    float* y             = (float*)(ws + 26214400);        // 8 MB
    float* Aa            = (float*)(ws + 34603008);        // 16 KB
    float* Sa            = (float*)(ws + 34619392);        // 16 KB
    unsigned short* w2t0 = (unsigned short*)(ws + 34635776);  // 8 KB
    unsigned short* w2t1 = (unsigned short*)(ws + 34643968);  // 32 KB
    unsigned short* w2t2 = (unsigned short*)(ws + 34676736);  // 128 KB
    unsigned short* w2t3 = (unsigned short*)(ws + 34807808);  // 512 KB
    unsigned short* w2t4 = (unsigned short*)(ws + 35332096);  // 512 KB
    float* acc           = (float*)(ws + 35856384);           // 160 KB: 5 x (4096+4096) floats
    float* s1l[5]; float* s2l[5];
    for (int l = 0; l < 5; ++l) { s1l[l] = acc + l * 8192; s2l[l] = s1l[l] + 4096; }

    // setup: w2 + w1(hi/lo) conversions + stat-zero + gn1 stats + kNN
    setup_kernel<<<N_NODES, 64, 0, stream>>>(pos, knn, cw2[0], cw2[1], cw2[2], cw2[3], cw2[4],
                                             cw1[3], cw1[4],
                                             w2t0, w2t1, w2t2, w2t3, w2t4,
                                             w1h4, w1l4b, w1h5, w1l5,
                                             acc, gnms[0], gnw[0], Aa, Sa);

    // Layer 1 (gn1 apply fused into node1, no relu)
    node_kernel<3, 64, 0, 0><<<N_NODES / 16, 64, 0, stream>>>(pos, pos, Aa, Sa, gnms[0], gnw[0], gnb[0], cw1[0], cb1[0], U, P);
    edge_kernel<64, 4><<<N_NODES, 256, 0, stream>>>(U, P, knn, w2t0, cb2[0], y, s1l[0], s2l[0]);

    // Layer 2 (stats from L1 edge atomics)
    node_kernel<64, 128, 1, 1><<<N_NODES / 16, 128, 0, stream>>>(y, pos, s1l[0], s2l[0], gnms[1], gnw[1], gnb[1], cw1[1], cb1[1], U, P);
    edge_kernel<128, 8><<<N_NODES, 512, 0, stream>>>(U, P, knn, w2t1, cb2[1], y, s1l[1], s2l[1]);

    // Layer 3
    node_kernel<128, 256, 1, 1><<<N_NODES / 16, 256, 0, stream>>>(y, pos, s1l[1], s2l[1], gnms[2], gnw[2], gnb[2], cw1[2], cb1[2], U, P);
    edgeb_kernel<256, 4><<<N_NODES / 2, 256, 0, stream>>>(U, P, knn, w2t2, cb2[2], y, s1l[2], s2l[2]);

    // Layer 4 (Markidis MFMA node)
    nodem_kernel<256><<<N_NODES / 16, 512, 0, stream>>>(y, pos, s1l[2], s2l[2], gnms[3], gnw[3], gnb[3],
                                                        w1h4, w1l4b, cw1[3], cb1[3], U, P);
    edgeb_kernel<512, 8><<<N_NODES / 2, 512, 0, stream>>>(U, P, knn, w2t3, cb2[3], y, s1l[3], s2l[3]);

    // Layer 5 (Markidis MFMA node)
    nodem_kernel<512><<<N_NODES / 16, 512, 0, stream>>>(y, pos, s1l[3], s2l[3], gnms[4], gnw[4], gnb[4],
                                                        w1h5, w1l5, cw1[4], cb1[4], U, P);
    edgeb_kernel<512, 8><<<N_NODES / 2, 512, 0, stream>>>(U, P, knn, w2t4, cb2[4], y, s1l[4], s2l[4]);

    // gn6 (stats from L5 edge atomics) fused into classifier
    cls_kernel<<<N_NODES / 16, 256, 0, stream>>>(y, s1l[4], s2l[4], gnms[5], gnw[5], gnb[5], clsw, clsb, out);
}

// Round 14
// 608.267 us; speedup vs baseline: 1.2036x; 1.0516x over previous
//
#include <hip/hip_runtime.h>
#include <stdint.h>

#define N_NODES 4096
#define NGRAPH 8
#define NPTS 512
#define KNN 64
#define EPSN 1e-5f

typedef _Float16 f16x8 __attribute__((ext_vector_type(8)));
typedef float f32x4 __attribute__((ext_vector_type(4)));
typedef unsigned long long u64;

__device__ __forceinline__ unsigned short f2h(float f) {
    _Float16 h = (_Float16)f;   // RNE, v_cvt_f16_f32
    union { _Float16 h; unsigned short u; } cv; cv.h = h;
    return cv.u;
}
__device__ __forceinline__ float h2f(unsigned short u) {
    union { unsigned short u; _Float16 h; } cv; cv.u = u;
    return (float)cv.h;
}

// Chunk-major w2 conversion: one thread -> one 8-half chunk (8 strided reads -> 1 coalesced 16B store).
__device__ __forceinline__ void w2cv8(const float* __restrict__ src, unsigned short* __restrict__ dst,
                                      int c, int lg2c) {
    int C = 1 << lg2c;
    int mm = c & 15, q = (c >> 4) & 3, F = c >> 6;
    int k5 = F & ((C >> 5) - 1), n4 = F >> (lg2c - 5);
    int n = n4 * 16 + mm, kb = k5 * 32 + q * 8;
    unsigned short h[8];
    #pragma unroll
    for (int t = 0; t < 8; ++t) h[t] = f2h(src[(size_t)(kb + t) * C + n]);
    uint4 pk;
    pk.x = (unsigned)h[0] | ((unsigned)h[1] << 16);
    pk.y = (unsigned)h[2] | ((unsigned)h[3] << 16);
    pk.z = (unsigned)h[4] | ((unsigned)h[5] << 16);
    pk.w = (unsigned)h[6] | ((unsigned)h[7] << 16);
    *(uint4*)&dst[(size_t)c * 8] = pk;
}

// w1 hi/lo converter for Markidis MFMA node. K x cout weights; kl = log2(K/32).
// Output layout identical to w2t read pattern with S32 = K/32, fragment = (n>>4)*S32 + k5.
__device__ __forceinline__ void w1cv8hl(const float* __restrict__ src, unsigned short* __restrict__ dh,
                                        unsigned short* __restrict__ dl, int c, int kl, int cout) {
    int mm = c & 15, q = (c >> 4) & 3, F = c >> 6;
    int k5 = F & ((1 << kl) - 1), n4 = F >> kl;
    int n = n4 * 16 + mm, kb = k5 * 32 + q * 8;
    unsigned short hh[8], ll[8];
    #pragma unroll
    for (int t = 0; t < 8; ++t) {
        float v = src[(size_t)(kb + t) * cout + n];
        hh[t] = f2h(v);
        ll[t] = f2h(v - h2f(hh[t]));
    }
    uint4 ph, pl;
    ph.x = (unsigned)hh[0] | ((unsigned)hh[1] << 16);
    ph.y = (unsigned)hh[2] | ((unsigned)hh[3] << 16);
    ph.z = (unsigned)hh[4] | ((unsigned)hh[5] << 16);
    ph.w = (unsigned)hh[6] | ((unsigned)hh[7] << 16);
    pl.x = (unsigned)ll[0] | ((unsigned)ll[1] << 16);
    pl.y = (unsigned)ll[2] | ((unsigned)ll[3] << 16);
    pl.z = (unsigned)ll[4] | ((unsigned)ll[5] << 16);
    pl.w = (unsigned)ll[6] | ((unsigned)ll[7] << 16);
    *(uint4*)&dh[(size_t)c * 8] = ph;
    *(uint4*)&dl[(size_t)c * 8] = pl;
}

// ---------------- setup: w2/w1 conversions + stat-zero + gn1 stats + kNN, one dispatch ----------------
__global__ __launch_bounds__(64) void setup_kernel(const float* __restrict__ pos, int* __restrict__ knn_out,
                                                   const float* __restrict__ wa, const float* __restrict__ wb,
                                                   const float* __restrict__ wc, const float* __restrict__ wd,
                                                   const float* __restrict__ we,
                                                   const float* __restrict__ w12, const float* __restrict__ w13,
                                                   const float* __restrict__ w14, const float* __restrict__ w15,
                                                   unsigned short* __restrict__ oa, unsigned short* __restrict__ ob,
                                                   unsigned short* __restrict__ oc, unsigned short* __restrict__ od,
                                                   unsigned short* __restrict__ oe,
                                                   unsigned short* __restrict__ o12h, unsigned short* __restrict__ o12l,
                                                   unsigned short* __restrict__ o13h, unsigned short* __restrict__ o13l,
                                                   unsigned short* __restrict__ o14h, unsigned short* __restrict__ o14l,
                                                   unsigned short* __restrict__ o15h, unsigned short* __restrict__ o15l,
                                                   float* __restrict__ statz,
                                                   const float* __restrict__ ms1, const float* __restrict__ gw1,
                                                   float* __restrict__ Aa, float* __restrict__ Sa) {
#pragma clang fp contract(off)
    __shared__ float px[NPTS], py[NPTS], pz[NPTS];
    __shared__ u64 keys[NPTS];
    int bid = blockIdx.x;
    int tid = threadIdx.x;   // 0..63
    int gidx = bid * 64 + tid;           // 0..262143
    for (int idx = gidx; idx < 40960; idx += 262144) statz[idx] = 0.f;
    // conversions (chunk = 8 halves):
    //   w2: [0,512) C=64; [512,2560) C=128; [2560,10752) C=256; [10752,43520) C=512; [43520,76288) C=512
    //   w1 hi/lo: L4 [76288,92672) K=256; L5 [92672,125440) K=512;
    //             L2 [125440,126464) K=64,cout=128; L3 [126464,130560) K=128,cout=256
    if (gidx < 130560) {
        int c = gidx;
        if (c < 512)          w2cv8(wa, oa, c, 6);
        else if (c < 2560)    w2cv8(wb, ob, c - 512, 7);
        else if (c < 10752)   w2cv8(wc, oc, c - 2560, 8);
        else if (c < 43520)   w2cv8(wd, od, c - 10752, 9);
        else if (c < 76288)   w2cv8(we, oe, c - 43520, 9);
        else if (c < 92672)   w1cv8hl(w14, o14h, o14l, c - 76288, 3, 512);
        else if (c < 125440)  w1cv8hl(w15, o15h, o15l, c - 92672, 4, 512);
        else if (c < 126464)  w1cv8hl(w12, o12h, o12l, c - 125440, 1, 128);
        else                  w1cv8hl(w13, o13h, o13l, c - 126464, 2, 256);
    }
    if (bid < 24) {   // gn1 stats: 24 (graph,channel) wave-jobs
        int g = bid / 3, ch = bid - g * 3;
        float s1 = 0.f, s2 = 0.f;
        for (int n = tid; n < NPTS; n += 64) {
            float v = pos[(g * NPTS + n) * 3 + ch];
            s1 += v; s2 += v * v;
        }
        #pragma unroll
        for (int off = 32; off; off >>= 1) { s1 += __shfl_xor(s1, off); s2 += __shfl_xor(s2, off); }
        if (tid == 0) {
            float mean = s1 * (1.f / NPTS);
            float av = mean * ms1[ch];
            float var = s2 * (1.f / NPTS) - 2.f * av * mean + av * av;
            Aa[g * 3 + ch] = av;
            Sa[g * 3 + ch] = gw1[ch] / sqrtf(var + EPSN);
        }
    }
    // ---- kNN: 1-wave bitonic sort of this dst point's 512 keys ----
    int b = bid >> 9;
    int il = bid & (NPTS - 1);
    for (int n = tid; n < NPTS; n += 64) {
        int base = (b * NPTS + n) * 3;
        px[n] = pos[base]; py[n] = pos[base + 1]; pz[n] = pos[base + 2];
    }
    __syncthreads();
    float xi = px[il], yi = py[il], zi = pz[il];
    for (int n = tid; n < NPTS; n += 64) {
        float dx = px[n] - xi, dy = py[n] - yi, dz = pz[n] - zi;
        float d2 = dx * dx;
        d2 = d2 + dy * dy;
        d2 = d2 + dz * dz;
        keys[n] = (((u64)__float_as_uint(d2)) << 32) | (unsigned)n;
    }
    __syncthreads();
    for (int k2 = 2; k2 <= NPTS; k2 <<= 1) {
        for (int j = k2 >> 1; j > 0; j >>= 1) {
            #pragma unroll 4
            for (int p = 0; p < 4; ++p) {
                int pid = tid + p * 64;
                int t = ((pid & ~(j - 1)) << 1) | (pid & (j - 1));
                int ixj = t | j;
                u64 a = keys[t], c = keys[ixj];
                bool up = ((t & k2) == 0);
                if ((a > c) == up) { keys[t] = c; keys[ixj] = a; }
            }
            __syncthreads();
        }
    }
    int j0 = (int)(keys[tid] & 0xffffffffu);
    knn_out[(size_t)(b * NPTS + il) * KNN + tid] = b * NPTS + j0;
}

// ---------------- Per-node MLP1 (scalar path, layer 1 only: CIN=3) ----------------
template<int CIN, int C, int RELU, int RAW>
__global__ __launch_bounds__(C) void node_kernel(const float* __restrict__ y, const float* __restrict__ pos,
                                                 const float* __restrict__ p1, const float* __restrict__ p2,
                                                 const float* __restrict__ ms, const float* __restrict__ gw,
                                                 const float* __restrict__ bnp,
                                                 const float* __restrict__ w1, const float* __restrict__ b1,
                                                 float* __restrict__ U, float* __restrict__ P) {
    constexpr int ROWS = 16;
    constexpr int KC = 64;
    constexpr int LDH = KC + 4;
    __shared__ float hs[ROWS][LDH];   // 4352 B
    __shared__ float As_[CIN > 0 ? CIN : 1], Ss_[CIN > 0 ? CIN : 1];
    const int c = threadIdx.x;
    const int n0 = blockIdx.x * ROWS;
    const int b = n0 >> 9;            // all 16 rows in one graph
    if (RAW) {
        for (int ch = c; ch < CIN; ch += C) {
            float s1 = p1[b * CIN + ch], s2 = p2[b * CIN + ch];
            float mean = s1 * (1.f / NPTS);
            float a = mean * ms[ch];
            float var = s2 * (1.f / NPTS) - 2.f * a * mean + a * a;
            As_[ch] = a;
            Ss_[ch] = gw[ch] / sqrtf(var + EPSN);
        }
    }
    float acc[ROWS];
    #pragma unroll
    for (int r = 0; r < ROWS; ++r) acc[r] = 0.f;
    constexpr int NCHUNK = (CIN + KC - 1) / KC;
    #pragma unroll 1
    for (int s = 0; s < NCHUNK; ++s) {
        const int k0 = s * KC;
        const int kc = (CIN - k0 < KC) ? (CIN - k0) : KC;
        __syncthreads();
        for (int idx = c; idx < ROWS * kc; idx += C) {
            int r = idx / kc, k = idx - r * kc;
            int ch = k0 + k;
            float a = RAW ? As_[ch] : p1[b * CIN + ch];
            float sf = RAW ? Ss_[ch] : p2[b * CIN + ch];
            float v = (y[(size_t)(n0 + r) * CIN + ch] - a) * sf + bnp[ch];
            if (RELU) v = fmaxf(v, 0.f);
            hs[r][k] = v;
        }
        __syncthreads();
        int k = 0;
        for (; k + 4 <= kc; k += 4) {
            float w0 = w1[(size_t)(k0 + k) * C + c];
            float w1v = w1[(size_t)(k0 + k + 1) * C + c];
            float w2v = w1[(size_t)(k0 + k + 2) * C + c];
            float w3v = w1[(size_t)(k0 + k + 3) * C + c];
            #pragma unroll
            for (int r = 0; r < ROWS; ++r) {
                f32x4 hv = *(const f32x4*)&hs[r][k];
                acc[r] = fmaf(hv[0], w0, acc[r]);
                acc[r] = fmaf(hv[1], w1v, acc[r]);
                acc[r] = fmaf(hv[2], w2v, acc[r]);
                acc[r] = fmaf(hv[3], w3v, acc[r]);
            }
        }
        for (; k < kc; ++k) {
            float wv = w1[(size_t)(k0 + k) * C + c];
            #pragma unroll
            for (int r = 0; r < ROWS; ++r)
                acc[r] = fmaf(hs[r][k], wv, acc[r]);
        }
    }
    float pacc[ROWS];
    #pragma unroll
    for (int r = 0; r < ROWS; ++r) pacc[r] = 0.f;
    #pragma unroll
    for (int e = 0; e < 3; ++e) {
        float wv = w1[(size_t)(CIN + e) * C + c];
        #pragma unroll
        for (int r = 0; r < ROWS; ++r)
            pacc[r] = fmaf(pos[(n0 + r) * 3 + e], wv, pacc[r]);
    }
    float bv = b1[c];
    #pragma unroll
    for (int r = 0; r < ROWS; ++r) {
        U[(size_t)(n0 + r) * C + c] = acc[r] + pacc[r] + bv;
        P[(size_t)(n0 + r) * C + c] = pacc[r];
    }
}

// ---------------- Per-node MLP1 via Markidis f16 hi/lo MFMA (layers 2-5) ----------------
// h@w1 = Ah*Bh + Al*Bh + Ah*Bl (f32 accumulate) -> error ~2^-22 relative, far below the f16
// message rounding already in the pipeline (bit-identical absmax verified in R13 for L4/L5).
// pos-part and bias stay exact f32 so U - P cancellation is preserved.
template<int CIN, int COUT>
__global__ __launch_bounds__(512) void nodem_kernel(const float* __restrict__ y, const float* __restrict__ pos,
                                                    const float* __restrict__ p1, const float* __restrict__ p2,
                                                    const float* __restrict__ ms, const float* __restrict__ gw,
                                                    const float* __restrict__ bnp,
                                                    const unsigned short* __restrict__ w1h,
                                                    const unsigned short* __restrict__ w1l,
                                                    const float* __restrict__ w1s, const float* __restrict__ b1,
                                                    float* __restrict__ U, float* __restrict__ P) {
    constexpr int S32 = CIN / 32;
    constexpr int NCHR = CIN / 8;          // 16B chunks per row
    constexpr int NCT = COUT / 128;        // col tiles per wave (8 waves x NCT x 16 = COUT)
    __shared__ unsigned short Ah[16 * CIN], Al[16 * CIN];
    __shared__ float As_[CIN], Ss_[CIN], pf[48];
    const int tid = threadIdx.x;
    const int n0 = blockIdx.x * 16;
    const int b = n0 >> 9;
    for (int ch = tid; ch < CIN; ch += 512) {
        float s1 = p1[b * CIN + ch], s2 = p2[b * CIN + ch];
        float mean = s1 * (1.f / NPTS);
        float a = mean * ms[ch];
        float var = s2 * (1.f / NPTS) - 2.f * a * mean + a * a;
        As_[ch] = a;
        Ss_[ch] = gw[ch] / sqrtf(var + EPSN);
    }
    if (tid < 48) pf[tid] = pos[n0 * 3 + tid];
    __syncthreads();
    // stage A (16 rows x CIN) as hi/lo f16, chunk-XOR swizzled (proven edge pattern)
    for (int ci = tid; ci < 2 * CIN; ci += 512) {
        int r = ci / NCHR, ch = ci - r * NCHR;
        int k0 = ch * 8;
        const float* yy = y + (size_t)(n0 + r) * CIN + k0;
        unsigned short hh[8], ll[8];
        #pragma unroll
        for (int t = 0; t < 8; ++t) {
            float v = (yy[t] - As_[k0 + t]) * Ss_[k0 + t] + bnp[k0 + t];
            v = fmaxf(v, 0.f);
            hh[t] = f2h(v);
            ll[t] = f2h(v - h2f(hh[t]));
        }
        int sc = (ch & ~7) | ((ch ^ r) & 7);
        uint4 ph, pl;
        ph.x = (unsigned)hh[0] | ((unsigned)hh[1] << 16);
        ph.y = (unsigned)hh[2] | ((unsigned)hh[3] << 16);
        ph.z = (unsigned)hh[4] | ((unsigned)hh[5] << 16);
        ph.w = (unsigned)hh[6] | ((unsigned)hh[7] << 16);
        pl.x = (unsigned)ll[0] | ((unsigned)ll[1] << 16);
        pl.y = (unsigned)ll[2] | ((unsigned)ll[3] << 16);
        pl.z = (unsigned)ll[4] | ((unsigned)ll[5] << 16);
        pl.w = (unsigned)ll[6] | ((unsigned)ll[7] << 16);
        *(uint4*)&Ah[r * CIN + sc * 8] = ph;
        *(uint4*)&Al[r * CIN + sc * 8] = pl;
    }
    __syncthreads();
    const int lane = tid & 63, wave = tid >> 6, m = lane & 15, quad = lane >> 4;
    const int cw = wave * (NCT * 16);
    f32x4 acc[NCT];
    f32x4 zero = {0.f, 0.f, 0.f, 0.f};
    #pragma unroll
    for (int ct = 0; ct < NCT; ++ct) acc[ct] = zero;
    const unsigned short* bh = w1h + (size_t)(cw >> 4) * S32 * 512 + quad * 128 + m * 8;
    const unsigned short* bl = w1l + (size_t)(cw >> 4) * S32 * 512 + quad * 128 + m * 8;
    #pragma unroll 2
    for (int s = 0; s < S32; ++s) {
        int ci = s * 4 + quad;
        int sc = (ci & ~7) | ((ci ^ m) & 7);
        f16x8 aH = *(const f16x8*)&Ah[m * CIN + sc * 8];
        f16x8 aL = *(const f16x8*)&Al[m * CIN + sc * 8];
        #pragma unroll
        for (int ct = 0; ct < NCT; ++ct) {
            f16x8 bH = *(const f16x8*)(bh + ((size_t)ct * S32 + s) * 512);
            f16x8 bL = *(const f16x8*)(bl + ((size_t)ct * S32 + s) * 512);
            acc[ct] = __builtin_amdgcn_mfma_f32_16x16x32_f16(aH, bH, acc[ct], 0, 0, 0);
            acc[ct] = __builtin_amdgcn_mfma_f32_16x16x32_f16(aL, bH, acc[ct], 0, 0, 0);
            acc[ct] = __builtin_amdgcn_mfma_f32_16x16x32_f16(aH, bL, acc[ct], 0, 0, 0);
        }
    }
    // epilogue: C/D layout col=lane&15, row=quad*4+reg (verified). pos-part + bias exact f32.
    #pragma unroll
    for (int ct = 0; ct < NCT; ++ct) {
        int col = cw + ct * 16 + m;
        float w0 = w1s[(size_t)CIN * COUT + col];
        float w1v = w1s[(size_t)(CIN + 1) * COUT + col];
        float w2v = w1s[(size_t)(CIN + 2) * COUT + col];
        float bc = b1[col];
        #pragma unroll
        for (int j = 0; j < 4; ++j) {
            int r = quad * 4 + j;
            float pp = pf[r * 3] * w0;
            pp = fmaf(pf[r * 3 + 1], w1v, pp);
            pp = fmaf(pf[r * 3 + 2], w2v, pp);
            float val = acc[ct][j] + pp + bc;
            U[(size_t)(n0 + r) * COUT + col] = val;
            P[(size_t)(n0 + r) * COUT + col] = pp;
        }
    }
}

// ---------------- Edge MLP2 (small C): round-2 proven monolithic-stage kernel ----------------
template<int C, int W>
__global__ __launch_bounds__(W * 64, 4) void edge_kernel(const float* __restrict__ U, const float* __restrict__ P,
                                                         const int* __restrict__ knn, const unsigned short* __restrict__ w2t,
                                                         const float* __restrict__ b2, float* __restrict__ Y,
                                                         float* __restrict__ sum1, float* __restrict__ sum2) {
    constexpr int NCT = C / (W * 16);    // col tiles per wave
    constexpr int S32 = C / 32;          // k32 tiles
    constexpr int NCHUNK = C / 8;        // 16B chunks per row
    __shared__ unsigned short Th[64 * C];   // full message tile, swizzled
    __shared__ int jn[64];
    __shared__ float Pr[C];              // block-uniform dst-row of P
    const int bid = blockIdx.x;
    const int i = ((bid & 7) << 9) | (bid >> 3);   // XCD = bid%8 = graph(i): gather stays in one L2
    const int tid = threadIdx.x;
    const int wave = tid >> 6, lane = tid & 63, m = lane & 15, quad = lane >> 4;
    const int cw = wave * (NCT * 16);
    if (tid < 64) jn[tid] = knn[(size_t)i * KNN + tid];
    for (int idx = tid; idx < C; idx += W * 64) Pr[idx] = P[(size_t)i * C + idx];
    __syncthreads();                     // jn + Pr visible
    #pragma unroll 2
    for (int idx = tid; idx < 64 * NCHUNK; idx += W * 64) {
        int row = idx / NCHUNK, ch = idx - row * NCHUNK;
        const float* up = U + (size_t)jn[row] * C + ch * 8;
        f32x4 va = *(const f32x4*)up;
        f32x4 vb = *(const f32x4*)(up + 4);
        f32x4 pa = *(const f32x4*)&Pr[ch * 8];
        f32x4 pb = *(const f32x4*)&Pr[ch * 8 + 4];
        uint4 pk;
        pk.x = (unsigned)f2h(fmaxf(va[0] - pa[0], 0.f)) | ((unsigned)f2h(fmaxf(va[1] - pa[1], 0.f)) << 16);
        pk.y = (unsigned)f2h(fmaxf(va[2] - pa[2], 0.f)) | ((unsigned)f2h(fmaxf(va[3] - pa[3], 0.f)) << 16);
        pk.z = (unsigned)f2h(fmaxf(vb[0] - pb[0], 0.f)) | ((unsigned)f2h(fmaxf(vb[1] - pb[1], 0.f)) << 16);
        pk.w = (unsigned)f2h(fmaxf(vb[2] - pb[2], 0.f)) | ((unsigned)f2h(fmaxf(vb[3] - pb[3], 0.f)) << 16);
        int sc = (ch & ~7) | ((ch ^ row) & 7);
        *(uint4*)&Th[row * C + sc * 8] = pk;
    }
    __syncthreads();
    f32x4 acc[4][NCT];
    f32x4 zero = {0.f, 0.f, 0.f, 0.f};
    #pragma unroll
    for (int rt = 0; rt < 4; ++rt)
        #pragma unroll
        for (int ct = 0; ct < NCT; ++ct)
            acc[rt][ct] = zero;
    #pragma unroll 2
    for (int s = 0; s < S32; ++s) {
        f16x8 a[4];
        #pragma unroll
        for (int rt = 0; rt < 4; ++rt) {
            int row = rt * 16 + m;
            int chunk = s * 4 + quad;
            int sc = (chunk & ~7) | ((chunk ^ row) & 7);
            a[rt] = *(const f16x8*)&Th[row * C + sc * 8];
        }
        #pragma unroll
        for (int ct = 0; ct < NCT; ++ct) {
            const f16x8 bb = *(const f16x8*)(w2t +
                (size_t)(((cw >> 4) + ct) * S32 + s) * 512 + quad * 128 + m * 8);
            #pragma unroll
            for (int rt = 0; rt < 4; ++rt)
                acc[rt][ct] = __builtin_amdgcn_mfma_f32_16x16x32_f16(a[rt], bb, acc[rt][ct], 0, 0, 0);
        }
    }
    const int gb = i >> 9;
    #pragma unroll
    for (int ct = 0; ct < NCT; ++ct) {
        float vmax = -3.4e38f;
        #pragma unroll
        for (int rt = 0; rt < 4; ++rt) {
            vmax = fmaxf(vmax, acc[rt][ct][0]);
            vmax = fmaxf(vmax, acc[rt][ct][1]);
            vmax = fmaxf(vmax, acc[rt][ct][2]);
            vmax = fmaxf(vmax, acc[rt][ct][3]);
        }
        vmax = fmaxf(vmax, __shfl_xor(vmax, 16));
        vmax = fmaxf(vmax, __shfl_xor(vmax, 32));
        if (quad == 0) {
            int col = cw + ct * 16 + m;
            float val = vmax + b2[col];
            Y[(size_t)i * C + col] = val;
            atomicAdd(&sum1[gb * C + col], val);
            atomicAdd(&sum2[gb * C + col], val * val);
        }
    }
}

__device__ __forceinline__ uint4 pack8(f32x4 va, f32x4 vb, f32x4 pa, f32x4 pb) {
    uint4 pk;
    pk.x = (unsigned)f2h(fmaxf(va[0] - pa[0], 0.f)) | ((unsigned)f2h(fmaxf(va[1] - pa[1], 0.f)) << 16);
    pk.y = (unsigned)f2h(fmaxf(va[2] - pa[2], 0.f)) | ((unsigned)f2h(fmaxf(va[3] - pa[3], 0.f)) << 16);
    pk.z = (unsigned)f2h(fmaxf(vb[0] - pb[0], 0.f)) | ((unsigned)f2h(fmaxf(vb[1] - pb[1], 0.f)) << 16);
    pk.w = (unsigned)f2h(fmaxf(vb[2] - pb[2], 0.f)) | ((unsigned)f2h(fmaxf(vb[3] - pb[3], 0.f)) << 16);
    return pk;
}

// ---------------- Edge MLP2 (large C): round-9 structure, W-parameterized.
// C=512,W=8: best measured config (1 block/CU). C=256,W=4: 66 KB LDS + 4-wave blocks
// -> 2 resident blocks/CU so stage/sweep anti-phase across blocks (validated R13).
template<int C, int W>
__global__ __launch_bounds__(W * 64, 2) void edgeb_kernel(const float* __restrict__ U, const float* __restrict__ P,
                                                          const int* __restrict__ knn, const unsigned short* __restrict__ w2t,
                                                          const float* __restrict__ b2, float* __restrict__ Y,
                                                          float* __restrict__ sum1, float* __restrict__ sum2) {
    constexpr int NCT = C / (W * 16);    // col tiles per wave (=4 for both configs)
    constexpr int S32 = C / 32;          // k32 tiles total
    constexpr int NCHK = C / 8;          // 16B chunks per row
    constexpr int RSTEP = (W * 64) / NCHK;   // staging rows per pass (=8 both)
    __shared__ unsigned short Th[(C / 64) * 128 * 64];   // chunk-major swizzled A-tile
    __shared__ int jn[128];
    const int bid = blockIdx.x;
    const int g = bid & 7;               // XCD = graph: U/P/w2t stay in one L2
    const int n0 = (g << 9) | ((bid >> 3) << 1);   // first of 2 dst nodes
    const int tid = threadIdx.x;
    const int lane = tid & 63, wave = tid >> 6, m = lane & 15, quad = lane >> 4;
    const int cw = wave * (NCT * 16);
    if (tid < 128) jn[tid] = knn[(size_t)(n0 + (tid >> 6)) * KNN + (tid & 63)];
    // per-thread fixed staging columns -> P values in registers (loaded once, pre-barrier)
    const int ch = tid & (NCHK - 1);     // chunk 0..NCHK-1
    const int rb = tid / NCHK;           // staging row base
    const int cblk = ch >> 3, cw8 = ch & 7;
    const float* pp = P + (size_t)n0 * C + ch * 8;
    f32x4 pa0 = *(const f32x4*)pp;
    f32x4 pb0 = *(const f32x4*)(pp + 4);
    f32x4 pa1 = *(const f32x4*)(pp + C);
    f32x4 pb1 = *(const f32x4*)(pp + C + 4);
    __syncthreads();                     // jn visible
    // ---- stage all 128 rows x C cols as f16 messages (measured: 0 bank conflicts) ----
    #pragma unroll 4
    for (int t = 0; t < 128 / RSTEP; ++t) {
        int row = rb + t * RSTEP;
        const float* up = U + (size_t)jn[row] * C + ch * 8;
        f32x4 va = *(const f32x4*)up;
        f32x4 vb = *(const f32x4*)(up + 4);
        f32x4 pa = (row & 64) ? pa1 : pa0;
        f32x4 pb = (row & 64) ? pb1 : pb0;
        *(uint4*)&Th[cblk * 8192 + row * 64 + ((cw8 ^ (row & 7)) << 3)] = pack8(va, vb, pa, pb);
    }
    __syncthreads();
    // ---- barrier-free MFMA sweep, zero per-read address VALU ----
    f32x4 acc[8][NCT];
    f32x4 zero = {0.f, 0.f, 0.f, 0.f};
    #pragma unroll
    for (int rt = 0; rt < 8; ++rt)
        #pragma unroll
        for (int ct = 0; ct < NCT; ++ct)
            acc[rt][ct] = zero;
    const unsigned short* wt = w2t + (size_t)(cw >> 4) * S32 * 512 + quad * 128 + m * 8;
    int idx0[8], idx1[8];                // A-tile element indices for even/odd k32-step parity
    #pragma unroll
    for (int rt = 0; rt < 8; ++rt) {
        int row = rt * 16 + m;
        idx0[rt] = row * 64 + ((quad ^ (row & 7)) << 3);
        idx1[rt] = row * 64 + (((4 + quad) ^ (row & 7)) << 3);
    }
    const unsigned short* pB[NCT];       // next-prefetch B pointers (s+2 targets)
    #pragma unroll
    for (int ct = 0; ct < NCT; ++ct)
        pB[ct] = wt + ((size_t)ct * S32 + 2) * 512;
    f16x8 bbA[NCT], bbB[NCT];
    #pragma unroll
    for (int ct = 0; ct < NCT; ++ct) {
        bbA[ct] = *(const f16x8*)(wt + (size_t)ct * S32 * 512);
        bbB[ct] = *(const f16x8*)(wt + ((size_t)ct * S32 + 1) * 512);
    }
    const unsigned short* tcur = Th;     // = Th + (s>>1)*8192
    auto step = [&](f16x8 (&buf)[NCT], const int (&idx)[8], int poff, bool pre) {
        f16x8 a[8];
        #pragma unroll
        for (int rt = 0; rt < 8; ++rt)
            a[rt] = *(const f16x8*)&tcur[idx[rt]];
        #pragma unroll
        for (int ct = 0; ct < NCT; ++ct) {
            f16x8 bcur = buf[ct];
            if (pre) buf[ct] = *(const f16x8*)(pB[ct] + poff);
            __builtin_amdgcn_s_setprio(1);
            #pragma unroll
            for (int rt = 0; rt < 8; ++rt)
                acc[rt][ct] = __builtin_amdgcn_mfma_f32_16x16x32_f16(a[rt], bcur, acc[rt][ct], 0, 0, 0);
            __builtin_amdgcn_s_setprio(0);
        }
    };
    #pragma unroll 1
    for (int s = 0; s + 2 < S32; s += 2) {
        step(bbA, idx0, 0, true);        // consume s,   prefetch s+2
        step(bbB, idx1, 512, true);      // consume s+1, prefetch s+3
        tcur += 8192;
        #pragma unroll
        for (int ct = 0; ct < NCT; ++ct) pB[ct] += 1024;
    }
    step(bbA, idx0, 0, false);           // s = S32-2
    step(bbB, idx1, 0, false);           // s = S32-1
    // ---- epilogue: scatter-max per node half (node h = rt>>2) ----
    #pragma unroll
    for (int h = 0; h < 2; ++h) {
        #pragma unroll
        for (int ct = 0; ct < NCT; ++ct) {
            float vmax = -3.4e38f;
            #pragma unroll
            for (int rt = h * 4; rt < h * 4 + 4; ++rt) {
                vmax = fmaxf(vmax, acc[rt][ct][0]);
                vmax = fmaxf(vmax, acc[rt][ct][1]);
                vmax = fmaxf(vmax, acc[rt][ct][2]);
                vmax = fmaxf(vmax, acc[rt][ct][3]);
            }
            vmax = fmaxf(vmax, __shfl_xor(vmax, 16));
            vmax = fmaxf(vmax, __shfl_xor(vmax, 32));
            if (quad == 0) {
                int col = cw + ct * 16 + m;
                float val = vmax + b2[col];
                Y[(size_t)(n0 + h) * C + col] = val;
                atomicAdd(&sum1[g * C + col], val);
                atomicAdd(&sum2[g * C + col], val * val);
            }
        }
    }
}

// ---------------- Classifier with fused gn6 (stats from atomic sums) ----------------
__global__ __launch_bounds__(256) void cls_kernel(const float* __restrict__ y, const float* __restrict__ sum1,
                                                  const float* __restrict__ sum2, const float* __restrict__ ms,
                                                  const float* __restrict__ gw, const float* __restrict__ gnb,
                                                  const float* __restrict__ w, const float* __restrict__ bias,
                                                  float* __restrict__ out) {
    __shared__ float wl[512 * 14];      // 28672 B
    __shared__ _Float16 hn[16][520];    // 16640 B (pad 8 -> 2-way LDS aliasing only)
    __shared__ float As[512], Ss[512];  // 4096 B
    int tid = threadIdx.x;
    int n0 = blockIdx.x * 16;
    int b = n0 >> 9;
    for (int ch = tid; ch < 512; ch += 256) {
        float s1 = sum1[b * 512 + ch], s2 = sum2[b * 512 + ch];
        float mean = s1 * (1.f / NPTS);
        float a = mean * ms[ch];
        float var = s2 * (1.f / NPTS) - 2.f * a * mean + a * a;
        As[ch] = a;
        Ss[ch] = gw[ch] / sqrtf(var + EPSN);
    }
    for (int idx = tid; idx < 512 * 14; idx += 256) wl[idx] = w[idx];
    __syncthreads();
    for (int idx = tid; idx < 16 * 512; idx += 256) {
        int r = idx >> 9, k = idx & 511;
        float v = (y[(size_t)(n0 + r) * 512 + k] - As[k]) * Ss[k] + gnb[k];
        hn[r][k] = (_Float16)fmaxf(v, 0.f);
    }
    __syncthreads();
    if (tid < 224) {
        int nl = tid / 14, c = tid - nl * 14;
        float acc = bias[c];
        for (int k = 0; k < 512; ++k)
            acc += (float)hn[nl][k] * wl[k * 14 + c];
        out[(size_t)(n0 + nl) * 14 + c] = acc;
    }
}

extern "C" void kernel_launch(void* const* d_in, const int* in_sizes, int n_in,
                              void* d_out, int out_size, void* d_ws, size_t ws_size,
                              hipStream_t stream) {
    const float* pos = (const float*)d_in[0];
    const float* gnw[6]; const float* gnb[6]; const float* gnms[6];
    for (int i = 0; i < 6; ++i) {
        gnw[i]  = (const float*)d_in[2 + 3 * i];
        gnb[i]  = (const float*)d_in[3 + 3 * i];
        gnms[i] = (const float*)d_in[4 + 3 * i];
    }
    const float* cw1[5]; const float* cb1[5]; const float* cw2[5]; const float* cb2[5];
    for (int i = 0; i < 5; ++i) {
        cw1[i] = (const float*)d_in[20 + 4 * i];
        cb1[i] = (const float*)d_in[21 + 4 * i];
        cw2[i] = (const float*)d_in[22 + 4 * i];
        cb2[i] = (const float*)d_in[23 + 4 * i];
    }
    const float* clsw = (const float*)d_in[40];
    const float* clsb = (const float*)d_in[41];
    float* out = (float*)d_out;

    char* ws = (char*)d_ws;
    int* knn             = (int*)(ws + 0);                 // 1 MB
    float* U             = (float*)(ws + 1048576);         // 8 MB
    float* P             = (float*)(ws + 9437184);         // 8 MB
    unsigned short* w1h4 = (unsigned short*)(ws + 17825792);  // 262144 B
    unsigned short* w1l4 = (unsigned short*)(ws + 18087936);  // 262144 B
    unsigned short* w1h5 = (unsigned short*)(ws + 18350080);  // 524288 B
    unsigned short* w1l5 = (unsigned short*)(ws + 18874368);  // 524288 B
    unsigned short* w1h2 = (unsigned short*)(ws + 19398656);  // 16384 B
    unsigned short* w1l2 = (unsigned short*)(ws + 19415040);  // 16384 B
    unsigned short* w1h3 = (unsigned short*)(ws + 19431424);  // 65536 B
    unsigned short* w1l3 = (unsigned short*)(ws + 19496960);  // 65536 B -> ends 19562496 < 26214400
    float* y             = (float*)(ws + 26214400);        // 8 MB
    float* Aa            = (float*)(ws + 34603008);        // 16 KB
    float* Sa            = (float*)(ws + 34619392);        // 16 KB
    unsigned short* w2t0 = (unsigned short*)(ws + 34635776);  // 8 KB
    unsigned short* w2t1 = (unsigned short*)(ws + 34643968);  // 32 KB
    unsigned short* w2t2 = (unsigned short*)(ws + 34676736);  // 128 KB
    unsigned short* w2t3 = (unsigned short*)(ws + 34807808);  // 512 KB
    unsigned short* w2t4 = (unsigned short*)(ws + 35332096);  // 512 KB
    float* acc           = (float*)(ws + 35856384);           // 160 KB: 5 x (4096+4096) floats
    float* s1l[5]; float* s2l[5];
    for (int l = 0; l < 5; ++l) { s1l[l] = acc + l * 8192; s2l[l] = s1l[l] + 4096; }

    // setup: w2 + w1(hi/lo, L2-L5) conversions + stat-zero + gn1 stats + kNN
    setup_kernel<<<N_NODES, 64, 0, stream>>>(pos, knn, cw2[0], cw2[1], cw2[2], cw2[3], cw2[4],
                                             cw1[1], cw1[2], cw1[3], cw1[4],
                                             w2t0, w2t1, w2t2, w2t3, w2t4,
                                             w1h2, w1l2, w1h3, w1l3, w1h4, w1l4, w1h5, w1l5,
                                             acc, gnms[0], gnw[0], Aa, Sa);

    // Layer 1 (gn1 apply fused into node1, no relu; CIN=3 stays scalar)
    node_kernel<3, 64, 0, 0><<<N_NODES / 16, 64, 0, stream>>>(pos, pos, Aa, Sa, gnms[0], gnw[0], gnb[0], cw1[0], cb1[0], U, P);
    edge_kernel<64, 4><<<N_NODES, 256, 0, stream>>>(U, P, knn, w2t0, cb2[0], y, s1l[0], s2l[0]);

    // Layer 2 (Markidis MFMA node, stats from L1 edge atomics)
    nodem_kernel<64, 128><<<N_NODES / 16, 512, 0, stream>>>(y, pos, s1l[0], s2l[0], gnms[1], gnw[1], gnb[1],
                                                            w1h2, w1l2, cw1[1], cb1[1], U, P);
    edge_kernel<128, 8><<<N_NODES, 512, 0, stream>>>(U, P, knn, w2t1, cb2[1], y, s1l[1], s2l[1]);

    // Layer 3 (Markidis MFMA node)
    nodem_kernel<128, 256><<<N_NODES / 16, 512, 0, stream>>>(y, pos, s1l[1], s2l[1], gnms[2], gnw[2], gnb[2],
                                                             w1h3, w1l3, cw1[2], cb1[2], U, P);
    edgeb_kernel<256, 4><<<N_NODES / 2, 256, 0, stream>>>(U, P, knn, w2t2, cb2[2], y, s1l[2], s2l[2]);

    // Layer 4 (Markidis MFMA node)
    nodem_kernel<256, 512><<<N_NODES / 16, 512, 0, stream>>>(y, pos, s1l[2], s2l[2], gnms[3], gnw[3], gnb[3],
                                                             w1h4, w1l4, cw1[3], cb1[3], U, P);
    edgeb_kernel<512, 8><<<N_NODES / 2, 512, 0, stream>>>(U, P, knn, w2t3, cb2[3], y, s1l[3], s2l[3]);

    // Layer 5 (Markidis MFMA node)
    nodem_kernel<512, 512><<<N_NODES / 16, 512, 0, stream>>>(y, pos, s1l[3], s2l[3], gnms[4], gnw[4], gnb[4],
                                                             w1h5, w1l5, cw1[4], cb1[4], U, P);
    edgeb_kernel<512, 8><<<N_NODES / 2, 512, 0, stream>>>(U, P, knn, w2t4, cb2[4], y, s1l[4], s2l[4]);

    // gn6 (stats from L5 edge atomics) fused into classifier
    cls_kernel<<<N_NODES / 16, 256, 0, stream>>>(y, s1l[4], s2l[4], gnms[5], gnw[5], gnb[5], clsw, clsb, out);
}

// Round 15
// 603.573 us; speedup vs baseline: 1.2129x; 1.0078x over previous
//
#include <hip/hip_runtime.h>
#include <stdint.h>

#define N_NODES 4096
#define NGRAPH 8
#define NPTS 512
#define KNN 64
#define EPSN 1e-5f

typedef _Float16 f16x8 __attribute__((ext_vector_type(8)));
typedef float f32x4 __attribute__((ext_vector_type(4)));
typedef unsigned long long u64;

__device__ __forceinline__ unsigned short f2h(float f) {
    _Float16 h = (_Float16)f;   // RNE, v_cvt_f16_f32
    union { _Float16 h; unsigned short u; } cv; cv.h = h;
    return cv.u;
}
__device__ __forceinline__ float h2f(unsigned short u) {
    union { unsigned short u; _Float16 h; } cv; cv.u = u;
    return (float)cv.h;
}

// Chunk-major w2 conversion: one thread -> one 8-half chunk (8 strided reads -> 1 coalesced 16B store).
__device__ __forceinline__ void w2cv8(const float* __restrict__ src, unsigned short* __restrict__ dst,
                                      int c, int lg2c) {
    int C = 1 << lg2c;
    int mm = c & 15, q = (c >> 4) & 3, F = c >> 6;
    int k5 = F & ((C >> 5) - 1), n4 = F >> (lg2c - 5);
    int n = n4 * 16 + mm, kb = k5 * 32 + q * 8;
    unsigned short h[8];
    #pragma unroll
    for (int t = 0; t < 8; ++t) h[t] = f2h(src[(size_t)(kb + t) * C + n]);
    uint4 pk;
    pk.x = (unsigned)h[0] | ((unsigned)h[1] << 16);
    pk.y = (unsigned)h[2] | ((unsigned)h[3] << 16);
    pk.z = (unsigned)h[4] | ((unsigned)h[5] << 16);
    pk.w = (unsigned)h[6] | ((unsigned)h[7] << 16);
    *(uint4*)&dst[(size_t)c * 8] = pk;
}

// w1 hi/lo converter for Markidis MFMA node. K x cout weights; kl = log2(K/32).
__device__ __forceinline__ void w1cv8hl(const float* __restrict__ src, unsigned short* __restrict__ dh,
                                        unsigned short* __restrict__ dl, int c, int kl, int cout) {
    int mm = c & 15, q = (c >> 4) & 3, F = c >> 6;
    int k5 = F & ((1 << kl) - 1), n4 = F >> kl;
    int n = n4 * 16 + mm, kb = k5 * 32 + q * 8;
    unsigned short hh[8], ll[8];
    #pragma unroll
    for (int t = 0; t < 8; ++t) {
        float v = src[(size_t)(kb + t) * cout + n];
        hh[t] = f2h(v);
        ll[t] = f2h(v - h2f(hh[t]));
    }
    uint4 ph, pl;
    ph.x = (unsigned)hh[0] | ((unsigned)hh[1] << 16);
    ph.y = (unsigned)hh[2] | ((unsigned)hh[3] << 16);
    ph.z = (unsigned)hh[4] | ((unsigned)hh[5] << 16);
    ph.w = (unsigned)hh[6] | ((unsigned)hh[7] << 16);
    pl.x = (unsigned)ll[0] | ((unsigned)ll[1] << 16);
    pl.y = (unsigned)ll[2] | ((unsigned)ll[3] << 16);
    pl.z = (unsigned)ll[4] | ((unsigned)ll[5] << 16);
    pl.w = (unsigned)ll[6] | ((unsigned)ll[7] << 16);
    *(uint4*)&dh[(size_t)c * 8] = ph;
    *(uint4*)&dl[(size_t)c * 8] = pl;
}

// ---------------- setup: w2/w1 conversions + stat-zero + gn1 stats + kNN, one dispatch ----------------
__global__ __launch_bounds__(64) void setup_kernel(const float* __restrict__ pos, int* __restrict__ knn_out,
                                                   const float* __restrict__ wa, const float* __restrict__ wb,
                                                   const float* __restrict__ wc, const float* __restrict__ wd,
                                                   const float* __restrict__ we,
                                                   const float* __restrict__ w12, const float* __restrict__ w13,
                                                   const float* __restrict__ w14, const float* __restrict__ w15,
                                                   unsigned short* __restrict__ oa, unsigned short* __restrict__ ob,
                                                   unsigned short* __restrict__ oc, unsigned short* __restrict__ od,
                                                   unsigned short* __restrict__ oe,
                                                   unsigned short* __restrict__ o12h, unsigned short* __restrict__ o12l,
                                                   unsigned short* __restrict__ o13h, unsigned short* __restrict__ o13l,
                                                   unsigned short* __restrict__ o14h, unsigned short* __restrict__ o14l,
                                                   unsigned short* __restrict__ o15h, unsigned short* __restrict__ o15l,
                                                   float* __restrict__ statz,
                                                   const float* __restrict__ ms1, const float* __restrict__ gw1,
                                                   float* __restrict__ Aa, float* __restrict__ Sa) {
#pragma clang fp contract(off)
    __shared__ float px[NPTS], py[NPTS], pz[NPTS];
    __shared__ u64 keys[NPTS];
    int bid = blockIdx.x;
    int tid = threadIdx.x;   // 0..63
    int gidx = bid * 64 + tid;           // 0..262143
    for (int idx = gidx; idx < 40960; idx += 262144) statz[idx] = 0.f;
    // conversions (chunk = 8 halves):
    //   w2: [0,512) C=64; [512,2560) C=128; [2560,10752) C=256; [10752,43520) C=512; [43520,76288) C=512
    //   w1 hi/lo: L4 [76288,92672) K=256; L5 [92672,125440) K=512;
    //             L2 [125440,126464) K=64,cout=128; L3 [126464,130560) K=128,cout=256
    if (gidx < 130560) {
        int c = gidx;
        if (c < 512)          w2cv8(wa, oa, c, 6);
        else if (c < 2560)    w2cv8(wb, ob, c - 512, 7);
        else if (c < 10752)   w2cv8(wc, oc, c - 2560, 8);
        else if (c < 43520)   w2cv8(wd, od, c - 10752, 9);
        else if (c < 76288)   w2cv8(we, oe, c - 43520, 9);
        else if (c < 92672)   w1cv8hl(w14, o14h, o14l, c - 76288, 3, 512);
        else if (c < 125440)  w1cv8hl(w15, o15h, o15l, c - 92672, 4, 512);
        else if (c < 126464)  w1cv8hl(w12, o12h, o12l, c - 125440, 1, 128);
        else                  w1cv8hl(w13, o13h, o13l, c - 126464, 2, 256);
    }
    if (bid < 24) {   // gn1 stats: 24 (graph,channel) wave-jobs
        int g = bid / 3, ch = bid - g * 3;
        float s1 = 0.f, s2 = 0.f;
        for (int n = tid; n < NPTS; n += 64) {
            float v = pos[(g * NPTS + n) * 3 + ch];
            s1 += v; s2 += v * v;
        }
        #pragma unroll
        for (int off = 32; off; off >>= 1) { s1 += __shfl_xor(s1, off); s2 += __shfl_xor(s2, off); }
        if (tid == 0) {
            float mean = s1 * (1.f / NPTS);
            float av = mean * ms1[ch];
            float var = s2 * (1.f / NPTS) - 2.f * av * mean + av * av;
            Aa[g * 3 + ch] = av;
            Sa[g * 3 + ch] = gw1[ch] / sqrtf(var + EPSN);
        }
    }
    // ---- kNN: 1-wave bitonic sort of this dst point's 512 keys ----
    int b = bid >> 9;
    int il = bid & (NPTS - 1);
    for (int n = tid; n < NPTS; n += 64) {
        int base = (b * NPTS + n) * 3;
        px[n] = pos[base]; py[n] = pos[base + 1]; pz[n] = pos[base + 2];
    }
    __syncthreads();
    float xi = px[il], yi = py[il], zi = pz[il];
    for (int n = tid; n < NPTS; n += 64) {
        float dx = px[n] - xi, dy = py[n] - yi, dz = pz[n] - zi;
        float d2 = dx * dx;
        d2 = d2 + dy * dy;
        d2 = d2 + dz * dz;
        keys[n] = (((u64)__float_as_uint(d2)) << 32) | (unsigned)n;
    }
    __syncthreads();
    for (int k2 = 2; k2 <= NPTS; k2 <<= 1) {
        for (int j = k2 >> 1; j > 0; j >>= 1) {
            #pragma unroll 4
            for (int p = 0; p < 4; ++p) {
                int pid = tid + p * 64;
                int t = ((pid & ~(j - 1)) << 1) | (pid & (j - 1));
                int ixj = t | j;
                u64 a = keys[t], c = keys[ixj];
                bool up = ((t & k2) == 0);
                if ((a > c) == up) { keys[t] = c; keys[ixj] = a; }
            }
            __syncthreads();
        }
    }
    int j0 = (int)(keys[tid] & 0xffffffffu);
    knn_out[(size_t)(b * NPTS + il) * KNN + tid] = b * NPTS + j0;
}

// ---------------- Per-node MLP1 (scalar path, layer 1 only: CIN=3) ----------------
template<int CIN, int C, int RELU, int RAW>
__global__ __launch_bounds__(C) void node_kernel(const float* __restrict__ y, const float* __restrict__ pos,
                                                 const float* __restrict__ p1, const float* __restrict__ p2,
                                                 const float* __restrict__ ms, const float* __restrict__ gw,
                                                 const float* __restrict__ bnp,
                                                 const float* __restrict__ w1, const float* __restrict__ b1,
                                                 float* __restrict__ U, float* __restrict__ P) {
    constexpr int ROWS = 16;
    constexpr int KC = 64;
    constexpr int LDH = KC + 4;
    __shared__ float hs[ROWS][LDH];   // 4352 B
    __shared__ float As_[CIN > 0 ? CIN : 1], Ss_[CIN > 0 ? CIN : 1];
    const int c = threadIdx.x;
    const int n0 = blockIdx.x * ROWS;
    const int b = n0 >> 9;            // all 16 rows in one graph
    if (RAW) {
        for (int ch = c; ch < CIN; ch += C) {
            float s1 = p1[b * CIN + ch], s2 = p2[b * CIN + ch];
            float mean = s1 * (1.f / NPTS);
            float a = mean * ms[ch];
            float var = s2 * (1.f / NPTS) - 2.f * a * mean + a * a;
            As_[ch] = a;
            Ss_[ch] = gw[ch] / sqrtf(var + EPSN);
        }
    }
    float acc[ROWS];
    #pragma unroll
    for (int r = 0; r < ROWS; ++r) acc[r] = 0.f;
    constexpr int NCHUNK = (CIN + KC - 1) / KC;
    #pragma unroll 1
    for (int s = 0; s < NCHUNK; ++s) {
        const int k0 = s * KC;
        const int kc = (CIN - k0 < KC) ? (CIN - k0) : KC;
        __syncthreads();
        for (int idx = c; idx < ROWS * kc; idx += C) {
            int r = idx / kc, k = idx - r * kc;
            int ch = k0 + k;
            float a = RAW ? As_[ch] : p1[b * CIN + ch];
            float sf = RAW ? Ss_[ch] : p2[b * CIN + ch];
            float v = (y[(size_t)(n0 + r) * CIN + ch] - a) * sf + bnp[ch];
            if (RELU) v = fmaxf(v, 0.f);
            hs[r][k] = v;
        }
        __syncthreads();
        int k = 0;
        for (; k + 4 <= kc; k += 4) {
            float w0 = w1[(size_t)(k0 + k) * C + c];
            float w1v = w1[(size_t)(k0 + k + 1) * C + c];
            float w2v = w1[(size_t)(k0 + k + 2) * C + c];
            float w3v = w1[(size_t)(k0 + k + 3) * C + c];
            #pragma unroll
            for (int r = 0; r < ROWS; ++r) {
                f32x4 hv = *(const f32x4*)&hs[r][k];
                acc[r] = fmaf(hv[0], w0, acc[r]);
                acc[r] = fmaf(hv[1], w1v, acc[r]);
                acc[r] = fmaf(hv[2], w2v, acc[r]);
                acc[r] = fmaf(hv[3], w3v, acc[r]);
            }
        }
        for (; k < kc; ++k) {
            float wv = w1[(size_t)(k0 + k) * C + c];
            #pragma unroll
            for (int r = 0; r < ROWS; ++r)
                acc[r] = fmaf(hs[r][k], wv, acc[r]);
        }
    }
    float pacc[ROWS];
    #pragma unroll
    for (int r = 0; r < ROWS; ++r) pacc[r] = 0.f;
    #pragma unroll
    for (int e = 0; e < 3; ++e) {
        float wv = w1[(size_t)(CIN + e) * C + c];
        #pragma unroll
        for (int r = 0; r < ROWS; ++r)
            pacc[r] = fmaf(pos[(n0 + r) * 3 + e], wv, pacc[r]);
    }
    float bv = b1[c];
    #pragma unroll
    for (int r = 0; r < ROWS; ++r) {
        U[(size_t)(n0 + r) * C + c] = acc[r] + pacc[r] + bv;
        P[(size_t)(n0 + r) * C + c] = pacc[r];
    }
}

// ---------------- Per-node MLP1 via Markidis f16 hi/lo MFMA (layers 2-5) ----------------
template<int CIN, int COUT>
__global__ __launch_bounds__(512) void nodem_kernel(const float* __restrict__ y, const float* __restrict__ pos,
                                                    const float* __restrict__ p1, const float* __restrict__ p2,
                                                    const float* __restrict__ ms, const float* __restrict__ gw,
                                                    const float* __restrict__ bnp,
                                                    const unsigned short* __restrict__ w1h,
                                                    const unsigned short* __restrict__ w1l,
                                                    const float* __restrict__ w1s, const float* __restrict__ b1,
                                                    float* __restrict__ U, float* __restrict__ P) {
    constexpr int S32 = CIN / 32;
    constexpr int NCHR = CIN / 8;          // 16B chunks per row
    constexpr int NCT = COUT / 128;        // col tiles per wave (8 waves x NCT x 16 = COUT)
    __shared__ unsigned short Ah[16 * CIN], Al[16 * CIN];
    __shared__ float As_[CIN], Ss_[CIN], pf[48];
    const int tid = threadIdx.x;
    const int n0 = blockIdx.x * 16;
    const int b = n0 >> 9;
    for (int ch = tid; ch < CIN; ch += 512) {
        float s1 = p1[b * CIN + ch], s2 = p2[b * CIN + ch];
        float mean = s1 * (1.f / NPTS);
        float a = mean * ms[ch];
        float var = s2 * (1.f / NPTS) - 2.f * a * mean + a * a;
        As_[ch] = a;
        Ss_[ch] = gw[ch] / sqrtf(var + EPSN);
    }
    if (tid < 48) pf[tid] = pos[n0 * 3 + tid];
    __syncthreads();
    // stage A (16 rows x CIN) as hi/lo f16, chunk-XOR swizzled (proven edge pattern)
    for (int ci = tid; ci < 2 * CIN; ci += 512) {
        int r = ci / NCHR, ch = ci - r * NCHR;
        int k0 = ch * 8;
        const float* yy = y + (size_t)(n0 + r) * CIN + k0;
        unsigned short hh[8], ll[8];
        #pragma unroll
        for (int t = 0; t < 8; ++t) {
            float v = (yy[t] - As_[k0 + t]) * Ss_[k0 + t] + bnp[k0 + t];
            v = fmaxf(v, 0.f);
            hh[t] = f2h(v);
            ll[t] = f2h(v - h2f(hh[t]));
        }
        int sc = (ch & ~7) | ((ch ^ r) & 7);
        uint4 ph, pl;
        ph.x = (unsigned)hh[0] | ((unsigned)hh[1] << 16);
        ph.y = (unsigned)hh[2] | ((unsigned)hh[3] << 16);
        ph.z = (unsigned)hh[4] | ((unsigned)hh[5] << 16);
        ph.w = (unsigned)hh[6] | ((unsigned)hh[7] << 16);
        pl.x = (unsigned)ll[0] | ((unsigned)ll[1] << 16);
        pl.y = (unsigned)ll[2] | ((unsigned)ll[3] << 16);
        pl.z = (unsigned)ll[4] | ((unsigned)ll[5] << 16);
        pl.w = (unsigned)ll[6] | ((unsigned)ll[7] << 16);
        *(uint4*)&Ah[r * CIN + sc * 8] = ph;
        *(uint4*)&Al[r * CIN + sc * 8] = pl;
    }
    __syncthreads();
    const int lane = tid & 63, wave = tid >> 6, m = lane & 15, quad = lane >> 4;
    const int cw = wave * (NCT * 16);
    f32x4 acc[NCT];
    f32x4 zero = {0.f, 0.f, 0.f, 0.f};
    #pragma unroll
    for (int ct = 0; ct < NCT; ++ct) acc[ct] = zero;
    const unsigned short* bh = w1h + (size_t)(cw >> 4) * S32 * 512 + quad * 128 + m * 8;
    const unsigned short* bl = w1l + (size_t)(cw >> 4) * S32 * 512 + quad * 128 + m * 8;
    #pragma unroll 2
    for (int s = 0; s < S32; ++s) {
        int ci = s * 4 + quad;
        int sc = (ci & ~7) | ((ci ^ m) & 7);
        f16x8 aH = *(const f16x8*)&Ah[m * CIN + sc * 8];
        f16x8 aL = *(const f16x8*)&Al[m * CIN + sc * 8];
        #pragma unroll
        for (int ct = 0; ct < NCT; ++ct) {
            f16x8 bH = *(const f16x8*)(bh + ((size_t)ct * S32 + s) * 512);
            f16x8 bL = *(const f16x8*)(bl + ((size_t)ct * S32 + s) * 512);
            acc[ct] = __builtin_amdgcn_mfma_f32_16x16x32_f16(aH, bH, acc[ct], 0, 0, 0);
            acc[ct] = __builtin_amdgcn_mfma_f32_16x16x32_f16(aL, bH, acc[ct], 0, 0, 0);
            acc[ct] = __builtin_amdgcn_mfma_f32_16x16x32_f16(aH, bL, acc[ct], 0, 0, 0);
        }
    }
    // epilogue: C/D layout col=lane&15, row=quad*4+reg (verified). pos-part + bias exact f32.
    #pragma unroll
    for (int ct = 0; ct < NCT; ++ct) {
        int col = cw + ct * 16 + m;
        float w0 = w1s[(size_t)CIN * COUT + col];
        float w1v = w1s[(size_t)(CIN + 1) * COUT + col];
        float w2v = w1s[(size_t)(CIN + 2) * COUT + col];
        float bc = b1[col];
        #pragma unroll
        for (int j = 0; j < 4; ++j) {
            int r = quad * 4 + j;
            float pp = pf[r * 3] * w0;
            pp = fmaf(pf[r * 3 + 1], w1v, pp);
            pp = fmaf(pf[r * 3 + 2], w2v, pp);
            float val = acc[ct][j] + pp + bc;
            U[(size_t)(n0 + r) * COUT + col] = val;
            P[(size_t)(n0 + r) * COUT + col] = pp;
        }
    }
}

__device__ __forceinline__ uint4 pack8(f32x4 va, f32x4 vb, f32x4 pa, f32x4 pb) {
    uint4 pk;
    pk.x = (unsigned)f2h(fmaxf(va[0] - pa[0], 0.f)) | ((unsigned)f2h(fmaxf(va[1] - pa[1], 0.f)) << 16);
    pk.y = (unsigned)f2h(fmaxf(va[2] - pa[2], 0.f)) | ((unsigned)f2h(fmaxf(va[3] - pa[3], 0.f)) << 16);
    pk.z = (unsigned)f2h(fmaxf(vb[0] - pb[0], 0.f)) | ((unsigned)f2h(fmaxf(vb[1] - pb[1], 0.f)) << 16);
    pk.w = (unsigned)f2h(fmaxf(vb[2] - pb[2], 0.f)) | ((unsigned)f2h(fmaxf(vb[3] - pb[3], 0.f)) << 16);
    return pk;
}

// ---------------- Edge MLP2 (all layers): round-9 structure, {C,W}-parameterized, 2 dst nodes/block.
// C=512,W=8: best measured (1 block/CU). C=256,W=4 / C=128,W=4 / C=64,W=2: smaller LDS ->
// multiple blocks/CU, stage/sweep anti-phase across blocks. Proven swizzle (0 conflicts measured).
template<int C, int W>
__global__ __launch_bounds__(W * 64, 2) void edgeb_kernel(const float* __restrict__ U, const float* __restrict__ P,
                                                          const int* __restrict__ knn, const unsigned short* __restrict__ w2t,
                                                          const float* __restrict__ b2, float* __restrict__ Y,
                                                          float* __restrict__ sum1, float* __restrict__ sum2) {
    constexpr int NCT = C / (W * 16);    // col tiles per wave
    constexpr int S32 = C / 32;          // k32 tiles total
    constexpr int NCHK = C / 8;          // 16B chunks per row
    constexpr int RSTEP = (W * 64) / NCHK;   // staging rows per pass
    __shared__ unsigned short Th[(C / 64) * 128 * 64];   // chunk-major swizzled A-tile
    __shared__ int jn[128];
    const int bid = blockIdx.x;
    const int g = bid & 7;               // XCD = graph: U/P/w2t stay in one L2
    const int n0 = (g << 9) | ((bid >> 3) << 1);   // first of 2 dst nodes
    const int tid = threadIdx.x;
    const int lane = tid & 63, wave = tid >> 6, m = lane & 15, quad = lane >> 4;
    const int cw = wave * (NCT * 16);
    if (tid < 128) jn[tid] = knn[(size_t)(n0 + (tid >> 6)) * KNN + (tid & 63)];
    // per-thread fixed staging columns -> P values in registers (loaded once, pre-barrier)
    const int ch = tid & (NCHK - 1);     // chunk 0..NCHK-1
    const int rb = tid / NCHK;           // staging row base
    const int cblk = ch >> 3, cw8 = ch & 7;
    const float* pp = P + (size_t)n0 * C + ch * 8;
    f32x4 pa0 = *(const f32x4*)pp;
    f32x4 pb0 = *(const f32x4*)(pp + 4);
    f32x4 pa1 = *(const f32x4*)(pp + C);
    f32x4 pb1 = *(const f32x4*)(pp + C + 4);
    __syncthreads();                     // jn visible
    // ---- stage all 128 rows x C cols as f16 messages (measured: 0 bank conflicts) ----
    #pragma unroll 4
    for (int t = 0; t < 128 / RSTEP; ++t) {
        int row = rb + t * RSTEP;
        const float* up = U + (size_t)jn[row] * C + ch * 8;
        f32x4 va = *(const f32x4*)up;
        f32x4 vb = *(const f32x4*)(up + 4);
        f32x4 pa = (row & 64) ? pa1 : pa0;
        f32x4 pb = (row & 64) ? pb1 : pb0;
        *(uint4*)&Th[cblk * 8192 + row * 64 + ((cw8 ^ (row & 7)) << 3)] = pack8(va, vb, pa, pb);
    }
    __syncthreads();
    // ---- barrier-free MFMA sweep, zero per-read address VALU ----
    f32x4 acc[8][NCT];
    f32x4 zero = {0.f, 0.f, 0.f, 0.f};
    #pragma unroll
    for (int rt = 0; rt < 8; ++rt)
        #pragma unroll
        for (int ct = 0; ct < NCT; ++ct)
            acc[rt][ct] = zero;
    const unsigned short* wt = w2t + (size_t)(cw >> 4) * S32 * 512 + quad * 128 + m * 8;
    int idx0[8], idx1[8];                // A-tile element indices for even/odd k32-step parity
    #pragma unroll
    for (int rt = 0; rt < 8; ++rt) {
        int row = rt * 16 + m;
        idx0[rt] = row * 64 + ((quad ^ (row & 7)) << 3);
        idx1[rt] = row * 64 + (((4 + quad) ^ (row & 7)) << 3);
    }
    const unsigned short* pB[NCT];       // next-prefetch B pointers (s+2 targets)
    #pragma unroll
    for (int ct = 0; ct < NCT; ++ct)
        pB[ct] = wt + ((size_t)ct * S32 + 2) * 512;
    f16x8 bbA[NCT], bbB[NCT];
    #pragma unroll
    for (int ct = 0; ct < NCT; ++ct) {
        bbA[ct] = *(const f16x8*)(wt + (size_t)ct * S32 * 512);
        bbB[ct] = *(const f16x8*)(wt + ((size_t)ct * S32 + 1) * 512);
    }
    const unsigned short* tcur = Th;     // = Th + (s>>1)*8192
    auto step = [&](f16x8 (&buf)[NCT], const int (&idx)[8], int poff, bool pre) {
        f16x8 a[8];
        #pragma unroll
        for (int rt = 0; rt < 8; ++rt)
            a[rt] = *(const f16x8*)&tcur[idx[rt]];
        #pragma unroll
        for (int ct = 0; ct < NCT; ++ct) {
            f16x8 bcur = buf[ct];
            if (pre) buf[ct] = *(const f16x8*)(pB[ct] + poff);
            __builtin_amdgcn_s_setprio(1);
            #pragma unroll
            for (int rt = 0; rt < 8; ++rt)
                acc[rt][ct] = __builtin_amdgcn_mfma_f32_16x16x32_f16(a[rt], bcur, acc[rt][ct], 0, 0, 0);
            __builtin_amdgcn_s_setprio(0);
        }
    };
    #pragma unroll 1
    for (int s = 0; s + 2 < S32; s += 2) {
        step(bbA, idx0, 0, true);        // consume s,   prefetch s+2
        step(bbB, idx1, 512, true);      // consume s+1, prefetch s+3
        tcur += 8192;
        #pragma unroll
        for (int ct = 0; ct < NCT; ++ct) pB[ct] += 1024;
    }
    step(bbA, idx0, 0, false);           // s = S32-2
    step(bbB, idx1, 0, false);           // s = S32-1
    // ---- epilogue: scatter-max per node half (node h = rt>>2) ----
    #pragma unroll
    for (int h = 0; h < 2; ++h) {
        #pragma unroll
        for (int ct = 0; ct < NCT; ++ct) {
            float vmax = -3.4e38f;
            #pragma unroll
            for (int rt = h * 4; rt < h * 4 + 4; ++rt) {
                vmax = fmaxf(vmax, acc[rt][ct][0]);
                vmax = fmaxf(vmax, acc[rt][ct][1]);
                vmax = fmaxf(vmax, acc[rt][ct][2]);
                vmax = fmaxf(vmax, acc[rt][ct][3]);
            }
            vmax = fmaxf(vmax, __shfl_xor(vmax, 16));
            vmax = fmaxf(vmax, __shfl_xor(vmax, 32));
            if (quad == 0) {
                int col = cw + ct * 16 + m;
                float val = vmax + b2[col];
                Y[(size_t)(n0 + h) * C + col] = val;
                atomicAdd(&sum1[g * C + col], val);
                atomicAdd(&sum2[g * C + col], val * val);
            }
        }
    }
}

// ---------------- Classifier with fused gn6 (stats from atomic sums) ----------------
__global__ __launch_bounds__(256) void cls_kernel(const float* __restrict__ y, const float* __restrict__ sum1,
                                                  const float* __restrict__ sum2, const float* __restrict__ ms,
                                                  const float* __restrict__ gw, const float* __restrict__ gnb,
                                                  const float* __restrict__ w, const float* __restrict__ bias,
                                                  float* __restrict__ out) {
    __shared__ float wl[512 * 14];      // 28672 B
    __shared__ _Float16 hn[16][520];    // 16640 B (pad 8 -> 2-way LDS aliasing only)
    __shared__ float As[512], Ss[512];  // 4096 B
    int tid = threadIdx.x;
    int n0 = blockIdx.x * 16;
    int b = n0 >> 9;
    for (int ch = tid; ch < 512; ch += 256) {
        float s1 = sum1[b * 512 + ch], s2 = sum2[b * 512 + ch];
        float mean = s1 * (1.f / NPTS);
        float a = mean * ms[ch];
        float var = s2 * (1.f / NPTS) - 2.f * a * mean + a * a;
        As[ch] = a;
        Ss[ch] = gw[ch] / sqrtf(var + EPSN);
    }
    for (int idx = tid; idx < 512 * 14; idx += 256) wl[idx] = w[idx];
    __syncthreads();
    for (int idx = tid; idx < 16 * 512; idx += 256) {
        int r = idx >> 9, k = idx & 511;
        float v = (y[(size_t)(n0 + r) * 512 + k] - As[k]) * Ss[k] + gnb[k];
        hn[r][k] = (_Float16)fmaxf(v, 0.f);
    }
    __syncthreads();
    if (tid < 224) {
        int nl = tid / 14, c = tid - nl * 14;
        float acc = bias[c];
        for (int k = 0; k < 512; ++k)
            acc += (float)hn[nl][k] * wl[k * 14 + c];
        out[(size_t)(n0 + nl) * 14 + c] = acc;
    }
}

extern "C" void kernel_launch(void* const* d_in, const int* in_sizes, int n_in,
                              void* d_out, int out_size, void* d_ws, size_t ws_size,
                              hipStream_t stream) {
    const float* pos = (const float*)d_in[0];
    const float* gnw[6]; const float* gnb[6]; const float* gnms[6];
    for (int i = 0; i < 6; ++i) {
        gnw[i]  = (const float*)d_in[2 + 3 * i];
        gnb[i]  = (const float*)d_in[3 + 3 * i];
        gnms[i] = (const float*)d_in[4 + 3 * i];
    }
    const float* cw1[5]; const float* cb1[5]; const float* cw2[5]; const float* cb2[5];
    for (int i = 0; i < 5; ++i) {
        cw1[i] = (const float*)d_in[20 + 4 * i];
        cb1[i] = (const float*)d_in[21 + 4 * i];
        cw2[i] = (const float*)d_in[22 + 4 * i];
        cb2[i] = (const float*)d_in[23 + 4 * i];
    }
    const float* clsw = (const float*)d_in[40];
    const float* clsb = (const float*)d_in[41];
    float* out = (float*)d_out;

    char* ws = (char*)d_ws;
    int* knn             = (int*)(ws + 0);                 // 1 MB
    float* U             = (float*)(ws + 1048576);         // 8 MB
    float* P             = (float*)(ws + 9437184);         // 8 MB
    unsigned short* w1h4 = (unsigned short*)(ws + 17825792);  // 262144 B
    unsigned short* w1l4 = (unsigned short*)(ws + 18087936);  // 262144 B
    unsigned short* w1h5 = (unsigned short*)(ws + 18350080);  // 524288 B
    unsigned short* w1l5 = (unsigned short*)(ws + 18874368);  // 524288 B
    unsigned short* w1h2 = (unsigned short*)(ws + 19398656);  // 16384 B
    unsigned short* w1l2 = (unsigned short*)(ws + 19415040);  // 16384 B
    unsigned short* w1h3 = (unsigned short*)(ws + 19431424);  // 65536 B
    unsigned short* w1l3 = (unsigned short*)(ws + 19496960);  // 65536 B -> ends 19562496 < 26214400
    float* y             = (float*)(ws + 26214400);        // 8 MB
    float* Aa            = (float*)(ws + 34603008);        // 16 KB
    float* Sa            = (float*)(ws + 34619392);        // 16 KB
    unsigned short* w2t0 = (unsigned short*)(ws + 34635776);  // 8 KB
    unsigned short* w2t1 = (unsigned short*)(ws + 34643968);  // 32 KB
    unsigned short* w2t2 = (unsigned short*)(ws + 34676736);  // 128 KB
    unsigned short* w2t3 = (unsigned short*)(ws + 34807808);  // 512 KB
    unsigned short* w2t4 = (unsigned short*)(ws + 35332096);  // 512 KB
    float* acc           = (float*)(ws + 35856384);           // 160 KB: 5 x (4096+4096) floats
    float* s1l[5]; float* s2l[5];
    for (int l = 0; l < 5; ++l) { s1l[l] = acc + l * 8192; s2l[l] = s1l[l] + 4096; }

    // setup: w2 + w1(hi/lo, L2-L5) conversions + stat-zero + gn1 stats + kNN
    setup_kernel<<<N_NODES, 64, 0, stream>>>(pos, knn, cw2[0], cw2[1], cw2[2], cw2[3], cw2[4],
                                             cw1[1], cw1[2], cw1[3], cw1[4],
                                             w2t0, w2t1, w2t2, w2t3, w2t4,
                                             w1h2, w1l2, w1h3, w1l3, w1h4, w1l4, w1h5, w1l5,
                                             acc, gnms[0], gnw[0], Aa, Sa);

    // Layer 1 (gn1 apply fused into node1, no relu; CIN=3 stays scalar)
    node_kernel<3, 64, 0, 0><<<N_NODES / 16, 64, 0, stream>>>(pos, pos, Aa, Sa, gnms[0], gnw[0], gnb[0], cw1[0], cb1[0], U, P);
    edgeb_kernel<64, 2><<<N_NODES / 2, 128, 0, stream>>>(U, P, knn, w2t0, cb2[0], y, s1l[0], s2l[0]);

    // Layer 2 (Markidis MFMA node, stats from L1 edge atomics)
    nodem_kernel<64, 128><<<N_NODES / 16, 512, 0, stream>>>(y, pos, s1l[0], s2l[0], gnms[1], gnw[1], gnb[1],
                                                            w1h2, w1l2, cw1[1], cb1[1], U, P);
    edgeb_kernel<128, 4><<<N_NODES / 2, 256, 0, stream>>>(U, P, knn, w2t1, cb2[1], y, s1l[1], s2l[1]);

    // Layer 3 (Markidis MFMA node)
    nodem_kernel<128, 256><<<N_NODES / 16, 512, 0, stream>>>(y, pos, s1l[1], s2l[1], gnms[2], gnw[2], gnb[2],
                                                             w1h3, w1l3, cw1[2], cb1[2], U, P);
    edgeb_kernel<256, 4><<<N_NODES / 2, 256, 0, stream>>>(U, P, knn, w2t2, cb2[2], y, s1l[2], s2l[2]);

    // Layer 4 (Markidis MFMA node)
    nodem_kernel<256, 512><<<N_NODES / 16, 512, 0, stream>>>(y, pos, s1l[2], s2l[2], gnms[3], gnw[3], gnb[3],
                                                             w1h4, w1l4, cw1[3], cb1[3], U, P);
    edgeb_kernel<512, 8><<<N_NODES / 2, 512, 0, stream>>>(U, P, knn, w2t3, cb2[3], y, s1l[3], s2l[3]);

    // Layer 5 (Markidis MFMA node)
    nodem_kernel<512, 512><<<N_NODES / 16, 512, 0, stream>>>(y, pos, s1l[3], s2l[3], gnms[4], gnw[4], gnb[4],
                                                             w1h5, w1l5, cw1[4], cb1[4], U, P);
    edgeb_kernel<512, 8><<<N_NODES / 2, 512, 0, stream>>>(U, P, knn, w2t4, cb2[4], y, s1l[4], s2l[4]);

    // gn6 (stats from L5 edge atomics) fused into classifier
    cls_kernel<<<N_NODES / 16, 256, 0, stream>>>(y, s1l[4], s2l[4], gnms[5], gnw[5], gnb[5], clsw, clsb, out);
}